// Round 6
// baseline (480.094 us; speedup 1.0000x reference)
//
#include <hip/hip_runtime.h>
#include <hip/hip_bf16.h>
#include <math.h>

typedef __attribute__((ext_vector_type(8))) short short8;
typedef __attribute__((ext_vector_type(4))) float f32x4;

#define NG 16   // flash j-groups

__device__ __forceinline__ unsigned short f2bf(float x) {
    __hip_bfloat16 b = __float2bfloat16(x);
    return *reinterpret_cast<unsigned short*>(&b);
}
__device__ __forceinline__ float bf2f(unsigned short u) {
    unsigned int t = ((unsigned int)u) << 16;
    float f;
    __builtin_memcpy(&f, &t, 4);
    return f;
}
__device__ __forceinline__ float gelu_exact(float x) {
    return 0.5f * x * (1.0f + erff(x * 0.70710678118654752f));
}

// ---------------------------------------------------------------- zero (diagnostic guard only)
__global__ __launch_bounds__(256) void k_zero(float* __restrict__ p, long n)
{
    long i = (long)blockIdx.x * 256 + threadIdx.x;
    if (i < n) p[i] = 0.f;
}

// ---------------------------------------------------------------- prologue: maskpack | wfold | LN(embed) | zero Oa+sA
__global__ __launch_bounds__(256) void k_prologue(
    const float* __restrict__ Aadj, unsigned long long* __restrict__ mask,
    const float* __restrict__ Wqkv, const float* __restrict__ Wout,
    float* __restrict__ Wfold,
    const float* __restrict__ embed, const float* __restrict__ g1,
    const float* __restrict__ b1, float* __restrict__ xn,
    float* __restrict__ Oa, float* __restrict__ sA)
{
    int bx = blockIdx.x, tid = threadIdx.x;
    if (bx < 4096) {                      // ---- mask pack
        if (!mask) return;
        int row = bx;
        int wave = tid >> 6, lane = tid & 63;
        for (int w = wave; w < 64; w += 4) {
            float a = Aadj[(long)row * 4096 + w * 64 + lane];
            unsigned long long m = __ballot(a > 0.f);
            if (lane == 0) mask[(long)row * 64 + w] = m;
        }
    } else if (bx < 4128) {               // ---- Wfold = Wqkv_v @ Wout [2][64,64]
        int bid = bx - 4096;
        int l = bid >> 4;
        int idx = (bid & 15) * 256 + tid;
        int c = idx >> 6, d = idx & 63;
        const float* Wq = Wqkv + (long)l * 64 * 768;
        const float* Wo = Wout + (long)l * 256 * 64;
        float a = 0.f;
        for (int k = 0; k < 256; ++k)
            a += Wq[c * 768 + 512 + k] * Wo[k * 64 + d];
        Wfold[l * 4096 + idx] = a;
    } else if (bx < 6176) {               // ---- layernorm(embed) -> xn
        int wave = tid >> 6, lane = tid & 63;
        long row = (long)(bx - 4128) * 4 + wave;
        float v = embed[row * 64 + lane];
        float s = v;
        #pragma unroll
        for (int o = 32; o; o >>= 1) s += __shfl_xor(s, o);
        float m = s * (1.0f / 64.0f);
        float d = v - m;
        float q = d * d;
        #pragma unroll
        for (int o = 32; o; o >>= 1) q += __shfl_xor(q, o);
        float rstd = rsqrtf(q * (1.0f / 64.0f) + 1e-5f);
        xn[row * 64 + lane] = d * rstd * g1[lane] + b1[lane];
    } else {                              // ---- zero Oa (2 MB) + sA (16 KB)
        long i = (long)(bx - 6176) * 256 + tid;
        if (i < 524288) Oa[i] = 0.f;
        else if (i < 528384) sA[i - 524288] = 0.f;
    }
}

// ---------------------------------------------------------------- merged q,k gemm + vWT gemm + OA rezero
// grid (64, 11): y<8 -> qk tile; y==8,9 -> vWT batch; y==10 -> zero OA (avcat accum)
__global__ __launch_bounds__(256) void k_qkx(
    const float* __restrict__ xn, const float* __restrict__ W,
    const float* __restrict__ Wfold,
    unsigned short* __restrict__ q, unsigned short* __restrict__ kmat,
    unsigned short* __restrict__ vWT, float* __restrict__ OA)
{
    __shared__ float As[64][65];
    __shared__ float Ws[64][65];
    int tid = threadIdx.x;
    int by = blockIdx.y;
    int tx = tid & 15, ty = tid >> 4;
    if (by == 10) {                       // zero OA [4096,128]
        long base = (long)blockIdx.x * 256 + tid;
        #pragma unroll
        for (int k = 0; k < 32; ++k) OA[base + (long)k * 16384] = 0.f;
        return;
    }
    if (by < 8) {
        int m0 = blockIdx.x * 64, n0 = by * 64;
        #pragma unroll
        for (int it = 0; it < 16; ++it) {
            int idx = tid + it * 256;
            int r = idx >> 6, c = idx & 63;
            As[r][c] = xn[(long)(m0 + r) * 64 + c];
            Ws[r][c] = W[(long)r * 768 + n0 + c];
        }
        __syncthreads();
        float acc[4][4] = {};
        #pragma unroll
        for (int k = 0; k < 64; ++k) {
            float a[4], w[4];
            #pragma unroll
            for (int i = 0; i < 4; ++i) a[i] = As[ty * 4 + i][k];
            #pragma unroll
            for (int j = 0; j < 4; ++j) w[j] = Ws[k][tx * 4 + j];
            #pragma unroll
            for (int i = 0; i < 4; ++i)
                #pragma unroll
                for (int j = 0; j < 4; ++j) acc[i][j] += a[i] * w[j];
        }
        #pragma unroll
        for (int i = 0; i < 4; ++i) {
            long row = m0 + ty * 4 + i;
            #pragma unroll
            for (int j = 0; j < 4; ++j) {
                int col = n0 + tx * 4 + j;
                if (col < 256) q[row * 256 + col] = f2bf(acc[i][j]);
                else           kmat[row * 256 + (col - 256)] = f2bf(acc[i][j]);
            }
        }
    } else {
        int n0 = blockIdx.x * 64, b = by - 8;
        #pragma unroll
        for (int it = 0; it < 16; ++it) {
            int idx = tid + it * 256;
            int r = idx >> 6, c = idx & 63;
            As[r][c] = xn[((long)b * 4096 + n0 + r) * 64 + c];
            Ws[r][c] = Wfold[r * 64 + c];
        }
        __syncthreads();
        float acc[4][4] = {};
        #pragma unroll
        for (int k = 0; k < 64; ++k) {
            float a[4], w[4];
            #pragma unroll
            for (int i = 0; i < 4; ++i) a[i] = As[ty * 4 + i][k];
            #pragma unroll
            for (int j = 0; j < 4; ++j) w[j] = Ws[k][tx * 4 + j];
            #pragma unroll
            for (int i = 0; i < 4; ++i)
                #pragma unroll
                for (int j = 0; j < 4; ++j) acc[i][j] += a[i] * w[j];
        }
        #pragma unroll
        for (int i = 0; i < 4; ++i)
            #pragma unroll
            for (int j = 0; j < 4; ++j)
                vWT[((long)b * 64 + tx * 4 + j) * 4096 + n0 + ty * 4 + i] = f2bf(acc[i][j]);
    }
}

// ---------------------------------------------------------------- flash attention (layer 0), fixed-M softmax
// P = exp(v - 8): per-group partials are plain sums -> atomicAdd into Oa/sA, no stats/rescale.
__global__ __launch_bounds__(256) void k_flash(
    const unsigned short* __restrict__ q, const unsigned short* __restrict__ kmat,
    const unsigned short* __restrict__ vwt,
    const unsigned long long* __restrict__ mask, const float* __restrict__ Aadj,
    float* __restrict__ Oa,    // [4096][128] fp32 accum (pre-zeroed)
    float* __restrict__ sA)    // [4096] fp32 accum (pre-zeroed)
{
    __shared__ __align__(16) unsigned short Qs[128 * 64];
    __shared__ __align__(16) unsigned short Ks[128 * 64];
    __shared__ __align__(16) unsigned short Ps[128 * 128];
    int tid = threadIdx.x;
    int lane = tid & 63, wq = tid >> 6;
    int fr = lane & 15, quad = lane >> 4;
    int m0 = blockIdx.x * 128;
    int g  = blockIdx.y;

    f32x4 accO[2][8];
    #pragma unroll
    for (int i = 0; i < 2; ++i)
        #pragma unroll
        for (int j = 0; j < 8; ++j) accO[i][j] = (f32x4){0.f, 0.f, 0.f, 0.f};
    float s_run[2] = {0.f, 0.f};

    for (int jt = 0; jt < 2; ++jt) {
        int jb = g * 256 + jt * 128;
        f32x4 accS[8][2];
        #pragma unroll
        for (int i = 0; i < 8; ++i)
            #pragma unroll
            for (int n = 0; n < 2; ++n) accS[i][n] = (f32x4){0.f, 0.f, 0.f, 0.f};
        for (int k0 = 0; k0 < 256; k0 += 64) {
            #pragma unroll
            for (int it = 0; it < 4; ++it) {
                int idx = tid + it * 256;
                int r = idx >> 3, c8 = (idx & 7) * 8;
                *(short8*)&Qs[idx * 8] = *(const short8*)(q    + (long)(m0 + r) * 256 + k0 + c8);
                *(short8*)&Ks[idx * 8] = *(const short8*)(kmat + (long)(jb + r) * 256 + k0 + c8);
            }
            __syncthreads();
            #pragma unroll
            for (int ks = 0; ks < 2; ++ks) {
                short8 ka[8], qb[2];
                #pragma unroll
                for (int i = 0; i < 8; ++i)
                    ka[i] = *(const short8*)&Ks[(i * 16 + fr) * 64 + ks * 32 + quad * 8];
                #pragma unroll
                for (int n = 0; n < 2; ++n)
                    qb[n] = *(const short8*)&Qs[(wq * 32 + n * 16 + fr) * 64 + ks * 32 + quad * 8];
                #pragma unroll
                for (int i = 0; i < 8; ++i)
                    #pragma unroll
                    for (int n = 0; n < 2; ++n)
                        accS[i][n] = __builtin_amdgcn_mfma_f32_16x16x32_bf16(
                            ka[i], qb[n], accS[i][n], 0, 0, 0);
            }
            __syncthreads();
        }
        // masked P = exp(v - 8); wave-private Ps rows; plain partial sums
        #pragma unroll
        for (int n = 0; n < 2; ++n) {
            int qrow = m0 + wq * 32 + n * 16 + fr;
            unsigned long long mw0 = 0, mw1 = 0;
            if (mask) {
                mw0 = mask[(long)qrow * 64 + (jb >> 6)];
                mw1 = mask[(long)qrow * 64 + (jb >> 6) + 1];
            }
            float ts = 0.f;
            int qrl = wq * 32 + n * 16 + fr;
            #pragma unroll
            for (int i = 0; i < 8; ++i) {
                float pr[4];
                #pragma unroll
                for (int r = 0; r < 4; ++r) {
                    int jl = i * 16 + quad * 4 + r;
                    float v = accS[i][n][r] * 0.125f;
                    bool keep = mask ? (((jl < 64 ? (mw0 >> jl) : (mw1 >> (jl - 64))) & 1ull) != 0)
                                     : (Aadj[(long)qrow * 4096 + jb + jl] > 0.f);
                    float p = keep ? __expf(v - 8.0f) : 0.0f;
                    if (jb + jl == qrow) p = 9.1188196555e-4f;  // exp(1-8)
                    pr[r] = p;
                    ts += p;
                }
                unsigned int lo = (unsigned int)f2bf(pr[0]) | ((unsigned int)f2bf(pr[1]) << 16);
                unsigned int hi = (unsigned int)f2bf(pr[2]) | ((unsigned int)f2bf(pr[3]) << 16);
                int u = (qrl * 128 + i * 16 + quad * 4) ^ ((fr & 7) << 3);
                *(uint2*)&Ps[u] = make_uint2(lo, hi);
            }
            ts += __shfl_xor(ts, 16);
            ts += __shfl_xor(ts, 32);
            s_run[n] += ts;
        }
        // stage V tile (Qs/Ks dead after S loop's trailing barrier)
        #pragma unroll
        for (int it = 0; it < 4; ++it) {
            int idx = tid + it * 256;
            int r = idx >> 3, c8 = (idx & 7) * 8;
            *(short8*)&Qs[idx * 8] = *(const short8*)(vwt + (long)r * 4096 + jb + c8);
            *(short8*)&Ks[idx * 8] = *(const short8*)(vwt + (long)r * 4096 + jb + 64 + c8);
        }
        __syncthreads();
        #pragma unroll
        for (int ks4 = 0; ks4 < 4; ++ks4) {
            const unsigned short* buf = (ks4 < 2) ? Qs : Ks;
            int ksl = ks4 & 1;
            short8 pa[2], vb[8];
            #pragma unroll
            for (int ii = 0; ii < 2; ++ii) {
                int u = ((wq * 32 + ii * 16 + fr) * 128 + ks4 * 32 + quad * 8) ^ ((fr & 7) << 3);
                pa[ii] = *(const short8*)&Ps[u];
            }
            #pragma unroll
            for (int nn = 0; nn < 8; ++nn)
                vb[nn] = *(const short8*)&buf[(nn * 16 + fr) * 64 + ksl * 32 + quad * 8];
            #pragma unroll
            for (int ii = 0; ii < 2; ++ii)
                #pragma unroll
                for (int nn = 0; nn < 8; ++nn)
                    accO[ii][nn] = __builtin_amdgcn_mfma_f32_16x16x32_bf16(
                        pa[ii], vb[nn], accO[ii][nn], 0, 0, 0);
        }
        __syncthreads();
    }
    // accumulate partial sums
    #pragma unroll
    for (int ii = 0; ii < 2; ++ii) {
        #pragma unroll
        for (int nn = 0; nn < 8; ++nn) {
            int ch = nn * 16 + fr;
            long rowb = m0 + wq * 32 + ii * 16 + quad * 4;
            #pragma unroll
            for (int r = 0; r < 4; ++r)
                atomicAdd(&Oa[(rowb + r) * 128 + ch], accO[ii][nn][r]);
        }
    }
    if (quad == 0) {
        #pragma unroll
        for (int n = 0; n < 2; ++n)
            atomicAdd(&sA[m0 + wq * 32 + n * 16 + fr], s_run[n]);
    }
}

// ---------------------------------------------------------------- dots GEMM (NT, bf16 in, bf16 out, strided ld)
__global__ __launch_bounds__(256) void k_mfma_nt(
    const unsigned short* __restrict__ A, const unsigned short* __restrict__ B,
    unsigned short* __restrict__ Cb, int ld, int K, float scale)
{
    __shared__ __align__(16) unsigned short As[128 * 64];
    __shared__ __align__(16) unsigned short Bs[128 * 64];
    int tid = threadIdx.x;
    int lane = tid & 63, wave = tid >> 6;
    long m0 = (long)blockIdx.x * 128, n0 = (long)blockIdx.y * 128;
    const unsigned short* Ag = A + m0 * K;
    const unsigned short* Bg = B + n0 * K;
    int wm = (wave & 1) * 64, wn = (wave >> 1) * 64;
    int fr = lane & 15, quad = lane >> 4;

    f32x4 acc[4][4];
    #pragma unroll
    for (int i = 0; i < 4; ++i)
        #pragma unroll
        for (int j = 0; j < 4; ++j) acc[i][j] = (f32x4){0.f, 0.f, 0.f, 0.f};

    for (int k0 = 0; k0 < K; k0 += 64) {
        #pragma unroll
        for (int it = 0; it < 4; ++it) {
            int c = tid + it * 256;
            int r = c >> 3, col = (c & 7) * 8;
            *(short8*)&As[c * 8] = *(const short8*)(Ag + (long)r * K + k0 + col);
            *(short8*)&Bs[c * 8] = *(const short8*)(Bg + (long)r * K + k0 + col);
        }
        __syncthreads();
        #pragma unroll
        for (int ks = 0; ks < 2; ++ks) {
            short8 af[4], bfr[4];
            #pragma unroll
            for (int i = 0; i < 4; ++i) {
                af[i]  = *(const short8*)&As[(wm + i * 16 + fr) * 64 + ks * 32 + quad * 8];
                bfr[i] = *(const short8*)&Bs[(wn + i * 16 + fr) * 64 + ks * 32 + quad * 8];
            }
            #pragma unroll
            for (int i = 0; i < 4; ++i)
                #pragma unroll
                for (int j = 0; j < 4; ++j)
                    acc[i][j] = __builtin_amdgcn_mfma_f32_16x16x32_bf16(
                        af[i], bfr[j], acc[i][j], 0, 0, 0);
        }
        __syncthreads();
    }
    #pragma unroll
    for (int i = 0; i < 4; ++i) {
        #pragma unroll
        for (int j = 0; j < 4; ++j) {
            long col = n0 + wn + j * 16 + fr;
            long rowb = m0 + wm + i * 16 + quad * 4;
            #pragma unroll
            for (int r = 0; r < 4; ++r)
                Cb[(rowb + r) * ld + col] = f2bf(acc[i][j][r] * scale);
        }
    }
}

// ---------------------------------------------------------------- block reduce helpers
__device__ __forceinline__ float block_max(float v, float* red, int lane, int wave) {
    #pragma unroll
    for (int o = 32; o; o >>= 1) v = fmaxf(v, __shfl_xor(v, o));
    if (lane == 0) red[wave] = v;
    __syncthreads();
    v = fmaxf(fmaxf(red[0], red[1]), fmaxf(red[2], red[3]));
    __syncthreads();
    return v;
}
__device__ __forceinline__ float block_sum(float v, float* red, int lane, int wave) {
    #pragma unroll
    for (int o = 32; o; o >>= 1) v += __shfl_xor(v, o);
    if (lane == 0) red[wave] = v;
    __syncthreads();
    v = red[0] + red[1] + red[2] + red[3];
    __syncthreads();
    return v;
}

// ---------------------------------------------------------------- dual softmax, bf16 strided in -> fp32 in-place
__global__ __launch_bounds__(256) void k_softmax_io(
    const unsigned short* __restrict__ dots_b, const float* __restrict__ Aadj,
    const unsigned long long* __restrict__ mask,
    float* __restrict__ attn, float* __restrict__ ds)
{
    __shared__ float red[4];
    __shared__ unsigned long long msk[64];
    int row = blockIdx.x, tid = threadIdx.x;
    int lane = tid & 63, wave = tid >> 6;
    if (mask) {
        if (tid < 64) msk[tid] = mask[(long)row * 64 + tid];
        __syncthreads();
    }
    const unsigned short* drow = dots_b + (long)row * 8192 + tid * 16;
    short8 dv0 = *(const short8*)drow;
    short8 dv1 = *(const short8*)(drow + 8);
    unsigned long long mword = mask ? msk[tid >> 2] : 0ull;
    int bitbase = (tid & 3) * 16;
    float d[16], mv[16];
    float mmax = -1e30f, umax = -1e30f;
    #pragma unroll
    for (int i = 0; i < 16; ++i) {
        unsigned short u = (unsigned short)(i < 8 ? dv0[i] : dv1[i - 8]);
        float dvf = bf2f(u);
        int j = tid * 16 + i;
        d[i] = dvf;
        bool keep = mask ? ((mword >> (bitbase + i)) & 1ull)
                         : (Aadj[(long)row * 4096 + j] > 0.f);
        float m = keep ? dvf : -1e30f;
        if (j == row) m = 1.0f;
        mv[i] = m;
        mmax = fmaxf(mmax, m);
        umax = fmaxf(umax, dvf);
    }
    float M1 = block_max(mmax, red, lane, wave);
    float s1 = 0.f;
    #pragma unroll
    for (int i = 0; i < 16; ++i) { float e = __expf(mv[i] - M1); mv[i] = e; s1 += e; }
    s1 = block_sum(s1, red, lane, wave);
    float inv1 = 1.0f / s1;
    float* arow = attn + (long)row * 4096 + tid * 16;
    *(float4*)(arow + 0)  = make_float4(mv[0]*inv1, mv[1]*inv1, mv[2]*inv1, mv[3]*inv1);
    *(float4*)(arow + 4)  = make_float4(mv[4]*inv1, mv[5]*inv1, mv[6]*inv1, mv[7]*inv1);
    *(float4*)(arow + 8)  = make_float4(mv[8]*inv1, mv[9]*inv1, mv[10]*inv1, mv[11]*inv1);
    *(float4*)(arow + 12) = make_float4(mv[12]*inv1, mv[13]*inv1, mv[14]*inv1, mv[15]*inv1);

    float M2 = block_max(umax, red, lane, wave);
    float s2 = 0.f;
    #pragma unroll
    for (int i = 0; i < 16; ++i) { float e = __expf(d[i] - M2); d[i] = e; s2 += e; }
    s2 = block_sum(s2, red, lane, wave);
    float inv2 = 1.0f / s2;
    float* srow = ds + (long)row * 4096 + tid * 16;
    *(float4*)(srow + 0)  = make_float4(d[0]*inv2, d[1]*inv2, d[2]*inv2, d[3]*inv2);
    *(float4*)(srow + 4)  = make_float4(d[4]*inv2, d[5]*inv2, d[6]*inv2, d[7]*inv2);
    *(float4*)(srow + 8)  = make_float4(d[8]*inv2, d[9]*inv2, d[10]*inv2, d[11]*inv2);
    *(float4*)(srow + 12) = make_float4(d[12]*inv2, d[13]*inv2, d[14]*inv2, d[15]*inv2);
}

// ---------------------------------------------------------------- attn@vWT split-K GEMM (fp32 A)
__global__ __launch_bounds__(256) void k_mfma_splitk(
    const float* __restrict__ A, const unsigned short* __restrict__ B,
    float* __restrict__ C)
{
    __shared__ __align__(16) unsigned short As[128 * 64];
    __shared__ __align__(16) unsigned short Bs[128 * 64];
    const int K = 4096, N = 128;
    int tid = threadIdx.x;
    int lane = tid & 63, wave = tid >> 6;
    long m0 = (long)blockIdx.x * 128;
    int k0base = blockIdx.y * 512;
    const float* Ag = A + m0 * K;
    int wm = (wave & 1) * 64, wn = (wave >> 1) * 64;
    int fr = lane & 15, quad = lane >> 4;

    f32x4 acc[4][4];
    #pragma unroll
    for (int i = 0; i < 4; ++i)
        #pragma unroll
        for (int j = 0; j < 4; ++j) acc[i][j] = (f32x4){0.f, 0.f, 0.f, 0.f};

    for (int k0 = k0base; k0 < k0base + 512; k0 += 64) {
        #pragma unroll
        for (int it = 0; it < 4; ++it) {
            int c = tid + it * 256;
            int r = c >> 3, col = (c & 7) * 8;
            float4 f0 = *(const float4*)(Ag + (long)r * K + k0 + col);
            float4 f1 = *(const float4*)(Ag + (long)r * K + k0 + col + 4);
            short8 s;
            s[0] = (short)f2bf(f0.x); s[1] = (short)f2bf(f0.y);
            s[2] = (short)f2bf(f0.z); s[3] = (short)f2bf(f0.w);
            s[4] = (short)f2bf(f1.x); s[5] = (short)f2bf(f1.y);
            s[6] = (short)f2bf(f1.z); s[7] = (short)f2bf(f1.w);
            *(short8*)&As[c * 8] = s;
            *(short8*)&Bs[c * 8] = *(const short8*)(B + (long)r * K + k0 + col);
        }
        __syncthreads();
        #pragma unroll
        for (int ks = 0; ks < 2; ++ks) {
            short8 af[4], bfr[4];
            #pragma unroll
            for (int i = 0; i < 4; ++i) {
                af[i]  = *(const short8*)&As[(wm + i * 16 + fr) * 64 + ks * 32 + quad * 8];
                bfr[i] = *(const short8*)&Bs[(wn + i * 16 + fr) * 64 + ks * 32 + quad * 8];
            }
            #pragma unroll
            for (int i = 0; i < 4; ++i)
                #pragma unroll
                for (int j = 0; j < 4; ++j)
                    acc[i][j] = __builtin_amdgcn_mfma_f32_16x16x32_bf16(
                        af[i], bfr[j], acc[i][j], 0, 0, 0);
        }
        __syncthreads();
    }
    #pragma unroll
    for (int i = 0; i < 4; ++i) {
        #pragma unroll
        for (int j = 0; j < 4; ++j) {
            long col = wn + j * 16 + fr;
            long rowb = m0 + wm + i * 16 + quad * 4;
            #pragma unroll
            for (int r = 0; r < 4; ++r)
                atomicAdd(&C[(rowb + r) * N + col], acc[i][j][r]);
        }
    }
}

// ---------------------------------------------------------------- x = xn + avcat + bout, then LN(g,b)
__global__ __launch_bounds__(256) void k_avres_ln(
    const float* __restrict__ xn, const float* __restrict__ avcat,
    const float* __restrict__ bout, const float* __restrict__ g,
    const float* __restrict__ b, float* __restrict__ out)
{
    int wave = threadIdx.x >> 6, lane = threadIdx.x & 63;
    long row = (long)blockIdx.x * 4 + wave;   // 8192 rows
    int bb = (int)(row >> 12), n = (int)(row & 4095);
    float v = xn[row * 64 + lane] + avcat[(long)n * 128 + bb * 64 + lane] + bout[lane];
    float s = v;
    #pragma unroll
    for (int o = 32; o; o >>= 1) s += __shfl_xor(s, o);
    float m = s * (1.0f / 64.0f);
    float d = v - m;
    float q = d * d;
    #pragma unroll
    for (int o = 32; o; o >>= 1) q += __shfl_xor(q, o);
    float rstd = rsqrtf(q * (1.0f / 64.0f) + 1e-5f);
    out[row * 64 + lane] = d * rstd * g[lane] + b[lane];
}

// ---------------------------------------------------------------- flash O/s combine + residual + LN (l0)
__global__ __launch_bounds__(256) void k_avres_ln_c(
    const float* __restrict__ xn, const float* __restrict__ Oa,
    const float* __restrict__ sA, const float* __restrict__ bout,
    const float* __restrict__ g, const float* __restrict__ b,
    float* __restrict__ out)
{
    int wave = threadIdx.x >> 6, lane = threadIdx.x & 63;
    long row = (long)blockIdx.x * 4 + wave;   // 8192 rows
    int bb = (int)(row >> 12), n = (int)(row & 4095);
    float av = Oa[(long)n * 128 + bb * 64 + lane] / sA[n];
    float v = xn[row * 64 + lane] + av + bout[lane];
    float s = v;
    #pragma unroll
    for (int o = 32; o; o >>= 1) s += __shfl_xor(s, o);
    float m = s * (1.0f / 64.0f);
    float d = v - m;
    float qv = d * d;
    #pragma unroll
    for (int o = 32; o; o >>= 1) qv += __shfl_xor(qv, o);
    float rstd = rsqrtf(qv * (1.0f / 64.0f) + 1e-5f);
    out[row * 64 + lane] = d * rstd * g[lane] + b[lane];
}

// ---------------------------------------------------------------- fused MLP + output layernorm (lean)
__global__ __launch_bounds__(256) void k_mlp(
    const float* __restrict__ xm,
    const float* __restrict__ W1, const float* __restrict__ bb1,
    const float* __restrict__ W2, const float* __restrict__ bb2,
    const float* __restrict__ g, const float* __restrict__ b,
    float* __restrict__ out)
{
    __shared__ float As[64][65];
    __shared__ float W1s[64][65];
    __shared__ float W2s[64][65];
    int tid = threadIdx.x;
    int m0 = blockIdx.x * 64;
    #pragma unroll
    for (int it = 0; it < 16; ++it) {
        int idx = tid + it * 256;
        int r = idx >> 6, c = idx & 63;
        As[r][c]  = xm[(long)(m0 + r) * 64 + c];
        W1s[r][c] = W1[(long)r * 64 + c];
        W2s[r][c] = W2[(long)r * 64 + c];
    }
    __syncthreads();
    int tx = tid & 15, ty = tid >> 4;
    float acc[4][4] = {};
    #pragma unroll
    for (int k = 0; k < 64; ++k) {
        float a[4], w[4];
        #pragma unroll
        for (int i = 0; i < 4; ++i) a[i] = As[ty * 4 + i][k];
        #pragma unroll
        for (int j = 0; j < 4; ++j) w[j] = W1s[k][tx * 4 + j];
        #pragma unroll
        for (int i = 0; i < 4; ++i)
            #pragma unroll
            for (int j = 0; j < 4; ++j) acc[i][j] += a[i] * w[j];
    }
    __syncthreads();
    #pragma unroll
    for (int i = 0; i < 4; ++i)
        #pragma unroll
        for (int j = 0; j < 4; ++j)
            W1s[ty * 4 + i][tx * 4 + j] = gelu_exact(acc[i][j] + bb1[tx * 4 + j]);
    __syncthreads();
    float acc2[4][4] = {};
    #pragma unroll
    for (int k = 0; k < 64; ++k) {
        float a[4], w[4];
        #pragma unroll
        for (int i = 0; i < 4; ++i) a[i] = W1s[ty * 4 + i][k];
        #pragma unroll
        for (int j = 0; j < 4; ++j) w[j] = W2s[k][tx * 4 + j];
        #pragma unroll
        for (int i = 0; i < 4; ++i)
            #pragma unroll
            for (int j = 0; j < 4; ++j) acc2[i][j] += a[i] * w[j];
    }
    #pragma unroll
    for (int i = 0; i < 4; ++i) {
        float v[4];
        float s = 0.f;
        #pragma unroll
        for (int j = 0; j < 4; ++j) {
            v[j] = acc2[i][j] + bb2[tx * 4 + j] + As[ty * 4 + i][tx * 4 + j];
            s += v[j];
        }
        #pragma unroll
        for (int o = 1; o < 16; o <<= 1) s += __shfl_xor(s, o);
        float m = s * (1.0f / 64.0f);
        float q = 0.f;
        #pragma unroll
        for (int j = 0; j < 4; ++j) { float d = v[j] - m; q += d * d; }
        #pragma unroll
        for (int o = 1; o < 16; o <<= 1) q += __shfl_xor(q, o);
        float rstd = rsqrtf(q * (1.0f / 64.0f) + 1e-5f);
        long row = m0 + ty * 4 + i;
        #pragma unroll
        for (int j = 0; j < 4; ++j) {
            int col = tx * 4 + j;
            out[row * 64 + col] = (v[j] - m) * rstd * g[col] + b[col];
        }
    }
}

// ---------------------------------------------------------------- launch
extern "C" void kernel_launch(void* const* d_in, const int* in_sizes, int n_in,
                              void* d_out, int out_size, void* d_ws, size_t ws_size,
                              hipStream_t stream)
{
    const float* embed = (const float*)d_in[0];
    const float* Aadj  = (const float*)d_in[1];
    const float* g1    = (const float*)d_in[2];
    const float* b1    = (const float*)d_in[3];
    const float* Wqkv  = (const float*)d_in[4];
    const float* Wout  = (const float*)d_in[5];
    const float* bout  = (const float*)d_in[6];
    const float* g2    = (const float*)d_in[7];
    const float* b2    = (const float*)d_in[8];
    const float* W1    = (const float*)d_in[9];
    const float* bb1   = (const float*)d_in[10];
    const float* W2    = (const float*)d_in[11];
    const float* bb2   = (const float*)d_in[12];
    const float* gf    = (const float*)d_in[13];
    const float* bff   = (const float*)d_in[14];

    // output regions (fp32): [x 524288 | attn 16777216 | ds 16777216]
    float* ox    = (float*)d_out;            // final x
    float* attnb = ox + 524288;              // attn output; l1 strided bf16 dots scratch
    float* dsb   = attnb + 16777216;         // ds output

    if (ws_size < (10ull << 20)) {           // diagnostic guard
        k_zero<<<133120, 256, 0, stream>>>(ox, 34078720l);
        return;
    }

    // workspace layout (unconditional 9.05 MB; mask +2 MB if available)
    char* ws = (char*)d_ws;
    float*          xn     = (float*)(ws + (0l << 20));            // 2 MB [8192,64]
    unsigned short* q      = (unsigned short*)(ws + (2l << 20));   // 2 MB [4096,256] bf16
    unsigned short* kmat   = (unsigned short*)(ws + (4l << 20));   // 2 MB [4096,256] bf16
    unsigned short* vwt    = (unsigned short*)(ws + (6l << 20));   // 1 MB [128,4096] bf16
    float*          OA     = (float*)(ws + (7l << 20));            // 2 MB [4096,128] O-accum / avcat
    float*          Wfold  = (float*)(ws + (9l << 20));            // 32 KB [2][64,64]
    float*          sA     = (float*)(ws + (9l << 20) + 32768);    // 16 KB [4096]
    unsigned long long* mask = (ws_size >= (12ull << 20))
        ? (unsigned long long*)(ws + (10l << 20)) : nullptr;       // 2 MB [4096,64]

    unsigned short* dots_b = (unsigned short*)attnb;               // l1: [4096] rows, stride 8192

    // -------- prologue: maskpack | Wfold(both) | LN(embed) | zero Oa+sA --------
    k_prologue<<<8240, 256, 0, stream>>>(Aadj, mask, Wqkv, Wout, Wfold,
                                         embed, g1, b1, xn, OA, sA);

    // -------- layer 0 (attn/ds are scratch -> fixed-M flash, atomic partials) --------
    k_qkx<<<dim3(64, 11), 256, 0, stream>>>(xn, Wqkv, Wfold, q, kmat, vwt, OA); // y=10 rezeros OA (no-op here)
    k_flash<<<dim3(32, NG), 256, 0, stream>>>(q, kmat, vwt, mask, Aadj, OA, sA);
    k_avres_ln_c<<<2048, 256, 0, stream>>>(xn, OA, sA, bout, g2, b2, xn);       // xm in place
    k_mlp<<<128, 256, 0, stream>>>(xn, W1, bb1, W2, bb2,
                                   g1 + 64, b1 + 64, xn);                       // -> next xn

    // -------- layer 1 (attn/ds are required fp32 outputs) --------
    k_qkx<<<dim3(64, 11), 256, 0, stream>>>(xn, Wqkv + 64 * 768, Wfold + 4096,
                                            q, kmat, vwt, OA);                  // y=10 rezeros OA for avcat
    k_mfma_nt<<<dim3(32, 32), 256, 0, stream>>>(q, kmat, dots_b, 8192, 256, 0.125f);
    k_softmax_io<<<4096, 256, 0, stream>>>(dots_b, Aadj, mask, attnb, dsb);
    k_mfma_splitk<<<dim3(32, 8), 256, 0, stream>>>(attnb, vwt, OA);
    k_avres_ln<<<2048, 256, 0, stream>>>(xn, OA, bout + 64, g2 + 64, b2 + 64, xn);
    k_mlp<<<128, 256, 0, stream>>>(xn, W1 + 4096, bb1 + 64, W2 + 4096, bb2 + 64,
                                   gf, bff, ox);                                // final LN -> out
}

// Round 7
// 465.088 us; speedup vs baseline: 1.0323x; 1.0323x over previous
//
#include <hip/hip_runtime.h>
#include <hip/hip_bf16.h>
#include <math.h>

typedef __attribute__((ext_vector_type(8))) short short8;
typedef __attribute__((ext_vector_type(4))) float f32x4;

#define NG 16   // flash j-groups

__device__ __forceinline__ unsigned short f2bf(float x) {
    __hip_bfloat16 b = __float2bfloat16(x);
    return *reinterpret_cast<unsigned short*>(&b);
}
__device__ __forceinline__ float bf2f(unsigned short u) {
    unsigned int t = ((unsigned int)u) << 16;
    float f;
    __builtin_memcpy(&f, &t, 4);
    return f;
}
__device__ __forceinline__ float gelu_exact(float x) {
    return 0.5f * x * (1.0f + erff(x * 0.70710678118654752f));
}

// ---------------------------------------------------------------- zero (diagnostic guard only)
__global__ __launch_bounds__(256) void k_zero(float* __restrict__ p, long n)
{
    long i = (long)blockIdx.x * 256 + threadIdx.x;
    if (i < n) p[i] = 0.f;
}

// ---------------------------------------------------------------- prologue: maskpack | wfold | LN(embed) | zero OA
__global__ __launch_bounds__(256) void k_prologue(
    const float* __restrict__ Aadj, unsigned long long* __restrict__ mask,
    const float* __restrict__ Wqkv, const float* __restrict__ Wout,
    float* __restrict__ Wfold,
    const float* __restrict__ embed, const float* __restrict__ g1,
    const float* __restrict__ b1, float* __restrict__ xn,
    float* __restrict__ OA)
{
    int bx = blockIdx.x, tid = threadIdx.x;
    if (bx < 4096) {                      // ---- mask pack
        if (!mask) return;
        int row = bx;
        int wave = tid >> 6, lane = tid & 63;
        for (int w = wave; w < 64; w += 4) {
            float a = Aadj[(long)row * 4096 + w * 64 + lane];
            unsigned long long m = __ballot(a > 0.f);
            if (lane == 0) mask[(long)row * 64 + w] = m;
        }
    } else if (bx < 4128) {               // ---- Wfold = Wqkv_v @ Wout [2][64,64]
        int bid = bx - 4096;
        int l = bid >> 4;
        int idx = (bid & 15) * 256 + tid;
        int c = idx >> 6, d = idx & 63;
        const float* Wq = Wqkv + (long)l * 64 * 768;
        const float* Wo = Wout + (long)l * 256 * 64;
        float a = 0.f;
        for (int k = 0; k < 256; ++k)
            a += Wq[c * 768 + 512 + k] * Wo[k * 64 + d];
        Wfold[l * 4096 + idx] = a;
    } else if (bx < 6176) {               // ---- layernorm(embed) -> xn
        int wave = tid >> 6, lane = tid & 63;
        long row = (long)(bx - 4128) * 4 + wave;
        float v = embed[row * 64 + lane];
        float s = v;
        #pragma unroll
        for (int o = 32; o; o >>= 1) s += __shfl_xor(s, o);
        float m = s * (1.0f / 64.0f);
        float d = v - m;
        float q = d * d;
        #pragma unroll
        for (int o = 32; o; o >>= 1) q += __shfl_xor(q, o);
        float rstd = rsqrtf(q * (1.0f / 64.0f) + 1e-5f);
        xn[row * 64 + lane] = d * rstd * g1[lane] + b1[lane];
    } else {                              // ---- zero OA accum (2 MB, used by l1 splitk)
        long i = (long)(bx - 6176) * 256 + tid;
        if (i < 524288) OA[i] = 0.f;
    }
}

// ---------------------------------------------------------------- merged q,k gemm + vWT gemm
// grid (64, 10): y<8 -> qk tile (n0=y*64); y>=8 -> vWT batch b=y-8
__global__ __launch_bounds__(256) void k_qkx(
    const float* __restrict__ xn, const float* __restrict__ W,
    const float* __restrict__ Wfold,
    unsigned short* __restrict__ q, unsigned short* __restrict__ kmat,
    unsigned short* __restrict__ vWT)
{
    __shared__ float As[64][65];
    __shared__ float Ws[64][65];
    int tid = threadIdx.x;
    int by = blockIdx.y;
    int tx = tid & 15, ty = tid >> 4;
    if (by < 8) {
        int m0 = blockIdx.x * 64, n0 = by * 64;
        #pragma unroll
        for (int it = 0; it < 16; ++it) {
            int idx = tid + it * 256;
            int r = idx >> 6, c = idx & 63;
            As[r][c] = xn[(long)(m0 + r) * 64 + c];
            Ws[r][c] = W[(long)r * 768 + n0 + c];
        }
        __syncthreads();
        float acc[4][4] = {};
        #pragma unroll
        for (int k = 0; k < 64; ++k) {
            float a[4], w[4];
            #pragma unroll
            for (int i = 0; i < 4; ++i) a[i] = As[ty * 4 + i][k];
            #pragma unroll
            for (int j = 0; j < 4; ++j) w[j] = Ws[k][tx * 4 + j];
            #pragma unroll
            for (int i = 0; i < 4; ++i)
                #pragma unroll
                for (int j = 0; j < 4; ++j) acc[i][j] += a[i] * w[j];
        }
        #pragma unroll
        for (int i = 0; i < 4; ++i) {
            long row = m0 + ty * 4 + i;
            #pragma unroll
            for (int j = 0; j < 4; ++j) {
                int col = n0 + tx * 4 + j;
                if (col < 256) q[row * 256 + col] = f2bf(acc[i][j]);
                else           kmat[row * 256 + (col - 256)] = f2bf(acc[i][j]);
            }
        }
    } else {
        int n0 = blockIdx.x * 64, b = by - 8;
        #pragma unroll
        for (int it = 0; it < 16; ++it) {
            int idx = tid + it * 256;
            int r = idx >> 6, c = idx & 63;
            As[r][c] = xn[((long)b * 4096 + n0 + r) * 64 + c];
            Ws[r][c] = Wfold[r * 64 + c];
        }
        __syncthreads();
        float acc[4][4] = {};
        #pragma unroll
        for (int k = 0; k < 64; ++k) {
            float a[4], w[4];
            #pragma unroll
            for (int i = 0; i < 4; ++i) a[i] = As[ty * 4 + i][k];
            #pragma unroll
            for (int j = 0; j < 4; ++j) w[j] = Ws[k][tx * 4 + j];
            #pragma unroll
            for (int i = 0; i < 4; ++i)
                #pragma unroll
                for (int j = 0; j < 4; ++j) acc[i][j] += a[i] * w[j];
        }
        #pragma unroll
        for (int i = 0; i < 4; ++i)
            #pragma unroll
            for (int j = 0; j < 4; ++j)
                vWT[((long)b * 64 + tx * 4 + j) * 4096 + n0 + ty * 4 + i] = f2bf(acc[i][j]);
    }
}

// ---------------------------------------------------------------- flash attention (layer 0), parts/stats
__global__ __launch_bounds__(256) void k_flash(
    const unsigned short* __restrict__ q, const unsigned short* __restrict__ kmat,
    const unsigned short* __restrict__ vwt,
    const unsigned long long* __restrict__ mask, const float* __restrict__ Aadj,
    unsigned short* __restrict__ part,   // [NG][4096][128] bf16
    float* __restrict__ stats)           // [NG][4096][2] (m, s)
{
    __shared__ __align__(16) unsigned short Qs[128 * 64];
    __shared__ __align__(16) unsigned short Ks[128 * 64];
    __shared__ __align__(16) unsigned short Ps[128 * 128];
    int tid = threadIdx.x;
    int lane = tid & 63, wq = tid >> 6;
    int fr = lane & 15, quad = lane >> 4;
    int m0 = blockIdx.x * 128;
    int g  = blockIdx.y;

    f32x4 accO[2][8];
    #pragma unroll
    for (int i = 0; i < 2; ++i)
        #pragma unroll
        for (int j = 0; j < 8; ++j) accO[i][j] = (f32x4){0.f, 0.f, 0.f, 0.f};
    float m_run[2] = {-1e30f, -1e30f};
    float s_run[2] = {0.f, 0.f};

    for (int jt = 0; jt < 2; ++jt) {
        int jb = g * 256 + jt * 128;
        f32x4 accS[8][2];
        #pragma unroll
        for (int i = 0; i < 8; ++i)
            #pragma unroll
            for (int n = 0; n < 2; ++n) accS[i][n] = (f32x4){0.f, 0.f, 0.f, 0.f};
        for (int k0 = 0; k0 < 256; k0 += 64) {
            #pragma unroll
            for (int it = 0; it < 4; ++it) {
                int idx = tid + it * 256;
                int r = idx >> 3, c8 = (idx & 7) * 8;
                *(short8*)&Qs[idx * 8] = *(const short8*)(q    + (long)(m0 + r) * 256 + k0 + c8);
                *(short8*)&Ks[idx * 8] = *(const short8*)(kmat + (long)(jb + r) * 256 + k0 + c8);
            }
            __syncthreads();
            #pragma unroll
            for (int ks = 0; ks < 2; ++ks) {
                short8 ka[8], qb[2];
                #pragma unroll
                for (int i = 0; i < 8; ++i)
                    ka[i] = *(const short8*)&Ks[(i * 16 + fr) * 64 + ks * 32 + quad * 8];
                #pragma unroll
                for (int n = 0; n < 2; ++n)
                    qb[n] = *(const short8*)&Qs[(wq * 32 + n * 16 + fr) * 64 + ks * 32 + quad * 8];
                #pragma unroll
                for (int i = 0; i < 8; ++i)
                    #pragma unroll
                    for (int n = 0; n < 2; ++n)
                        accS[i][n] = __builtin_amdgcn_mfma_f32_16x16x32_bf16(
                            ka[i], qb[n], accS[i][n], 0, 0, 0);
            }
            __syncthreads();
        }
        float al[2];
        #pragma unroll
        for (int n = 0; n < 2; ++n) {
            int qrow = m0 + wq * 32 + n * 16 + fr;
            unsigned long long mw0 = 0, mw1 = 0;
            if (mask) {
                mw0 = mask[(long)qrow * 64 + (jb >> 6)];
                mw1 = mask[(long)qrow * 64 + (jb >> 6) + 1];
            }
            float tm = -1e30f;
            #pragma unroll
            for (int i = 0; i < 8; ++i) {
                #pragma unroll
                for (int r = 0; r < 4; ++r) {
                    int jl = i * 16 + quad * 4 + r;
                    float v = accS[i][n][r] * 0.125f;
                    bool keep = mask ? (((jl < 64 ? (mw0 >> jl) : (mw1 >> (jl - 64))) & 1ull) != 0)
                                     : (Aadj[(long)qrow * 4096 + jb + jl] > 0.f);
                    v = keep ? v : -1e30f;
                    if (jb + jl == qrow) v = 1.0f;
                    accS[i][n][r] = v;
                    tm = fmaxf(tm, v);
                }
            }
            tm = fmaxf(tm, __shfl_xor(tm, 16));
            tm = fmaxf(tm, __shfl_xor(tm, 32));
            float mnew = fmaxf(fmaxf(m_run[n], tm), -1e20f);
            al[n] = __expf(m_run[n] - mnew);
            m_run[n] = mnew;
            float ts = 0.f;
            int qrl = wq * 32 + n * 16 + fr;
            #pragma unroll
            for (int i = 0; i < 8; ++i) {
                float p0 = __expf(accS[i][n][0] - mnew);
                float p1 = __expf(accS[i][n][1] - mnew);
                float p2 = __expf(accS[i][n][2] - mnew);
                float p3 = __expf(accS[i][n][3] - mnew);
                ts += (p0 + p1) + (p2 + p3);
                unsigned int lo = (unsigned int)f2bf(p0) | ((unsigned int)f2bf(p1) << 16);
                unsigned int hi = (unsigned int)f2bf(p2) | ((unsigned int)f2bf(p3) << 16);
                int u = (qrl * 128 + i * 16 + quad * 4) ^ ((fr & 7) << 3);
                *(uint2*)&Ps[u] = make_uint2(lo, hi);
            }
            ts += __shfl_xor(ts, 16);
            ts += __shfl_xor(ts, 32);
            s_run[n] = s_run[n] * al[n] + ts;
        }
        #pragma unroll
        for (int ii = 0; ii < 2; ++ii) {
            float av[4];
            #pragma unroll
            for (int r = 0; r < 4; ++r) av[r] = __shfl(al[ii], quad * 4 + r);
            #pragma unroll
            for (int nn = 0; nn < 8; ++nn)
                #pragma unroll
                for (int r = 0; r < 4; ++r) accO[ii][nn][r] *= av[r];
        }
        #pragma unroll
        for (int it = 0; it < 4; ++it) {
            int idx = tid + it * 256;
            int r = idx >> 3, c8 = (idx & 7) * 8;
            *(short8*)&Qs[idx * 8] = *(const short8*)(vwt + (long)r * 4096 + jb + c8);
            *(short8*)&Ks[idx * 8] = *(const short8*)(vwt + (long)r * 4096 + jb + 64 + c8);
        }
        __syncthreads();
        #pragma unroll
        for (int ks4 = 0; ks4 < 4; ++ks4) {
            const unsigned short* buf = (ks4 < 2) ? Qs : Ks;
            int ksl = ks4 & 1;
            short8 pa[2], vb[8];
            #pragma unroll
            for (int ii = 0; ii < 2; ++ii) {
                int u = ((wq * 32 + ii * 16 + fr) * 128 + ks4 * 32 + quad * 8) ^ ((fr & 7) << 3);
                pa[ii] = *(const short8*)&Ps[u];
            }
            #pragma unroll
            for (int nn = 0; nn < 8; ++nn)
                vb[nn] = *(const short8*)&buf[(nn * 16 + fr) * 64 + ksl * 32 + quad * 8];
            #pragma unroll
            for (int ii = 0; ii < 2; ++ii)
                #pragma unroll
                for (int nn = 0; nn < 8; ++nn)
                    accO[ii][nn] = __builtin_amdgcn_mfma_f32_16x16x32_bf16(
                        pa[ii], vb[nn], accO[ii][nn], 0, 0, 0);
        }
        __syncthreads();
    }
    #pragma unroll
    for (int ii = 0; ii < 2; ++ii) {
        #pragma unroll
        for (int nn = 0; nn < 8; ++nn) {
            int ch = nn * 16 + fr;
            long rowb = m0 + wq * 32 + ii * 16 + quad * 4;
            #pragma unroll
            for (int r = 0; r < 4; ++r)
                part[((long)g * 4096 + rowb + r) * 128 + ch] = f2bf(accO[ii][nn][r]);
        }
    }
    if (quad == 0) {
        #pragma unroll
        for (int n = 0; n < 2; ++n) {
            int qrow = m0 + wq * 32 + n * 16 + fr;
            stats[((long)g * 4096 + qrow) * 2]     = m_run[n];
            stats[((long)g * 4096 + qrow) * 2 + 1] = s_run[n];
        }
    }
}

// ---------------------------------------------------------------- dots GEMM (NT, bf16 in, bf16 out, strided ld)
__global__ __launch_bounds__(256) void k_mfma_nt(
    const unsigned short* __restrict__ A, const unsigned short* __restrict__ B,
    unsigned short* __restrict__ Cb, int ld, int K, float scale)
{
    __shared__ __align__(16) unsigned short As[128 * 64];
    __shared__ __align__(16) unsigned short Bs[128 * 64];
    int tid = threadIdx.x;
    int lane = tid & 63, wave = tid >> 6;
    long m0 = (long)blockIdx.x * 128, n0 = (long)blockIdx.y * 128;
    const unsigned short* Ag = A + m0 * K;
    const unsigned short* Bg = B + n0 * K;
    int wm = (wave & 1) * 64, wn = (wave >> 1) * 64;
    int fr = lane & 15, quad = lane >> 4;

    f32x4 acc[4][4];
    #pragma unroll
    for (int i = 0; i < 4; ++i)
        #pragma unroll
        for (int j = 0; j < 4; ++j) acc[i][j] = (f32x4){0.f, 0.f, 0.f, 0.f};

    for (int k0 = 0; k0 < K; k0 += 64) {
        #pragma unroll
        for (int it = 0; it < 4; ++it) {
            int c = tid + it * 256;
            int r = c >> 3, col = (c & 7) * 8;
            *(short8*)&As[c * 8] = *(const short8*)(Ag + (long)r * K + k0 + col);
            *(short8*)&Bs[c * 8] = *(const short8*)(Bg + (long)r * K + k0 + col);
        }
        __syncthreads();
        #pragma unroll
        for (int ks = 0; ks < 2; ++ks) {
            short8 af[4], bfr[4];
            #pragma unroll
            for (int i = 0; i < 4; ++i) {
                af[i]  = *(const short8*)&As[(wm + i * 16 + fr) * 64 + ks * 32 + quad * 8];
                bfr[i] = *(const short8*)&Bs[(wn + i * 16 + fr) * 64 + ks * 32 + quad * 8];
            }
            #pragma unroll
            for (int i = 0; i < 4; ++i)
                #pragma unroll
                for (int j = 0; j < 4; ++j)
                    acc[i][j] = __builtin_amdgcn_mfma_f32_16x16x32_bf16(
                        af[i], bfr[j], acc[i][j], 0, 0, 0);
        }
        __syncthreads();
    }
    #pragma unroll
    for (int i = 0; i < 4; ++i) {
        #pragma unroll
        for (int j = 0; j < 4; ++j) {
            long col = n0 + wn + j * 16 + fr;
            long rowb = m0 + wm + i * 16 + quad * 4;
            #pragma unroll
            for (int r = 0; r < 4; ++r)
                Cb[(rowb + r) * ld + col] = f2bf(acc[i][j][r] * scale);
        }
    }
}

// ---------------------------------------------------------------- block reduce helpers
__device__ __forceinline__ float block_max(float v, float* red, int lane, int wave) {
    #pragma unroll
    for (int o = 32; o; o >>= 1) v = fmaxf(v, __shfl_xor(v, o));
    if (lane == 0) red[wave] = v;
    __syncthreads();
    v = fmaxf(fmaxf(red[0], red[1]), fmaxf(red[2], red[3]));
    __syncthreads();
    return v;
}
__device__ __forceinline__ float block_sum(float v, float* red, int lane, int wave) {
    #pragma unroll
    for (int o = 32; o; o >>= 1) v += __shfl_xor(v, o);
    if (lane == 0) red[wave] = v;
    __syncthreads();
    v = red[0] + red[1] + red[2] + red[3];
    __syncthreads();
    return v;
}

// ---------------------------------------------------------------- dual softmax, bf16 strided in -> fp32 in-place
__global__ __launch_bounds__(256) void k_softmax_io(
    const unsigned short* __restrict__ dots_b, const float* __restrict__ Aadj,
    const unsigned long long* __restrict__ mask,
    float* __restrict__ attn, float* __restrict__ ds)
{
    __shared__ float red[4];
    __shared__ unsigned long long msk[64];
    int row = blockIdx.x, tid = threadIdx.x;
    int lane = tid & 63, wave = tid >> 6;
    if (mask) {
        if (tid < 64) msk[tid] = mask[(long)row * 64 + tid];
        __syncthreads();
    }
    const unsigned short* drow = dots_b + (long)row * 8192 + tid * 16;
    short8 dv0 = *(const short8*)drow;
    short8 dv1 = *(const short8*)(drow + 8);
    unsigned long long mword = mask ? msk[tid >> 2] : 0ull;
    int bitbase = (tid & 3) * 16;
    float d[16], mv[16];
    float mmax = -1e30f, umax = -1e30f;
    #pragma unroll
    for (int i = 0; i < 16; ++i) {
        unsigned short u = (unsigned short)(i < 8 ? dv0[i] : dv1[i - 8]);
        float dvf = bf2f(u);
        int j = tid * 16 + i;
        d[i] = dvf;
        bool keep = mask ? ((mword >> (bitbase + i)) & 1ull)
                         : (Aadj[(long)row * 4096 + j] > 0.f);
        float m = keep ? dvf : -1e30f;
        if (j == row) m = 1.0f;
        mv[i] = m;
        mmax = fmaxf(mmax, m);
        umax = fmaxf(umax, dvf);
    }
    float M1 = block_max(mmax, red, lane, wave);
    float s1 = 0.f;
    #pragma unroll
    for (int i = 0; i < 16; ++i) { float e = __expf(mv[i] - M1); mv[i] = e; s1 += e; }
    s1 = block_sum(s1, red, lane, wave);
    float inv1 = 1.0f / s1;
    float* arow = attn + (long)row * 4096 + tid * 16;
    *(float4*)(arow + 0)  = make_float4(mv[0]*inv1, mv[1]*inv1, mv[2]*inv1, mv[3]*inv1);
    *(float4*)(arow + 4)  = make_float4(mv[4]*inv1, mv[5]*inv1, mv[6]*inv1, mv[7]*inv1);
    *(float4*)(arow + 8)  = make_float4(mv[8]*inv1, mv[9]*inv1, mv[10]*inv1, mv[11]*inv1);
    *(float4*)(arow + 12) = make_float4(mv[12]*inv1, mv[13]*inv1, mv[14]*inv1, mv[15]*inv1);

    float M2 = block_max(umax, red, lane, wave);
    float s2 = 0.f;
    #pragma unroll
    for (int i = 0; i < 16; ++i) { float e = __expf(d[i] - M2); d[i] = e; s2 += e; }
    s2 = block_sum(s2, red, lane, wave);
    float inv2 = 1.0f / s2;
    float* srow = ds + (long)row * 4096 + tid * 16;
    *(float4*)(srow + 0)  = make_float4(d[0]*inv2, d[1]*inv2, d[2]*inv2, d[3]*inv2);
    *(float4*)(srow + 4)  = make_float4(d[4]*inv2, d[5]*inv2, d[6]*inv2, d[7]*inv2);
    *(float4*)(srow + 8)  = make_float4(d[8]*inv2, d[9]*inv2, d[10]*inv2, d[11]*inv2);
    *(float4*)(srow + 12) = make_float4(d[12]*inv2, d[13]*inv2, d[14]*inv2, d[15]*inv2);
}

// ---------------------------------------------------------------- attn@vWT split-K GEMM (fp32 A)
__global__ __launch_bounds__(256) void k_mfma_splitk(
    const float* __restrict__ A, const unsigned short* __restrict__ B,
    float* __restrict__ C)
{
    __shared__ __align__(16) unsigned short As[128 * 64];
    __shared__ __align__(16) unsigned short Bs[128 * 64];
    const int K = 4096, N = 128;
    int tid = threadIdx.x;
    int lane = tid & 63, wave = tid >> 6;
    long m0 = (long)blockIdx.x * 128;
    int k0base = blockIdx.y * 512;
    const float* Ag = A + m0 * K;
    int wm = (wave & 1) * 64, wn = (wave >> 1) * 64;
    int fr = lane & 15, quad = lane >> 4;

    f32x4 acc[4][4];
    #pragma unroll
    for (int i = 0; i < 4; ++i)
        #pragma unroll
        for (int j = 0; j < 4; ++j) acc[i][j] = (f32x4){0.f, 0.f, 0.f, 0.f};

    for (int k0 = k0base; k0 < k0base + 512; k0 += 64) {
        #pragma unroll
        for (int it = 0; it < 4; ++it) {
            int c = tid + it * 256;
            int r = c >> 3, col = (c & 7) * 8;
            float4 f0 = *(const float4*)(Ag + (long)r * K + k0 + col);
            float4 f1 = *(const float4*)(Ag + (long)r * K + k0 + col + 4);
            short8 s;
            s[0] = (short)f2bf(f0.x); s[1] = (short)f2bf(f0.y);
            s[2] = (short)f2bf(f0.z); s[3] = (short)f2bf(f0.w);
            s[4] = (short)f2bf(f1.x); s[5] = (short)f2bf(f1.y);
            s[6] = (short)f2bf(f1.z); s[7] = (short)f2bf(f1.w);
            *(short8*)&As[c * 8] = s;
            *(short8*)&Bs[c * 8] = *(const short8*)(B + (long)r * K + k0 + col);
        }
        __syncthreads();
        #pragma unroll
        for (int ks = 0; ks < 2; ++ks) {
            short8 af[4], bfr[4];
            #pragma unroll
            for (int i = 0; i < 4; ++i) {
                af[i]  = *(const short8*)&As[(wm + i * 16 + fr) * 64 + ks * 32 + quad * 8];
                bfr[i] = *(const short8*)&Bs[(wn + i * 16 + fr) * 64 + ks * 32 + quad * 8];
            }
            #pragma unroll
            for (int i = 0; i < 4; ++i)
                #pragma unroll
                for (int j = 0; j < 4; ++j)
                    acc[i][j] = __builtin_amdgcn_mfma_f32_16x16x32_bf16(
                        af[i], bfr[j], acc[i][j], 0, 0, 0);
        }
        __syncthreads();
    }
    #pragma unroll
    for (int i = 0; i < 4; ++i) {
        #pragma unroll
        for (int j = 0; j < 4; ++j) {
            long col = wn + j * 16 + fr;
            long rowb = m0 + wm + i * 16 + quad * 4;
            #pragma unroll
            for (int r = 0; r < 4; ++r)
                atomicAdd(&C[(rowb + r) * N + col], acc[i][j][r]);
        }
    }
}

// ---------------------------------------------------------------- flash-combine + residual + LN (l0)
__global__ __launch_bounds__(256) void k_avres_ln_c(
    const float* __restrict__ xn, const unsigned short* __restrict__ part,
    const float* __restrict__ stats, const float* __restrict__ bout,
    const float* __restrict__ g, const float* __restrict__ b,
    float* __restrict__ out)
{
    int wave = threadIdx.x >> 6, lane = threadIdx.x & 63;
    long row = (long)blockIdx.x * 4 + wave;   // 8192 rows
    int bb = (int)(row >> 12), n = (int)(row & 4095);
    float sm[NG], ss[NG];
    float ms = -1e30f;
    #pragma unroll
    for (int gg = 0; gg < NG; ++gg) {
        sm[gg] = stats[((long)gg * 4096 + n) * 2];
        ss[gg] = stats[((long)gg * 4096 + n) * 2 + 1];
        ms = fmaxf(ms, sm[gg]);
    }
    float acc = 0.f, stot = 0.f;
    #pragma unroll
    for (int gg = 0; gg < NG; ++gg) {
        float w = __expf(sm[gg] - ms);
        stot += w * ss[gg];
        acc  += w * bf2f(part[((long)gg * 4096 + n) * 128 + bb * 64 + lane]);
    }
    float v = xn[row * 64 + lane] + acc / stot + bout[lane];
    float s = v;
    #pragma unroll
    for (int o = 32; o; o >>= 1) s += __shfl_xor(s, o);
    float m = s * (1.0f / 64.0f);
    float d = v - m;
    float qv = d * d;
    #pragma unroll
    for (int o = 32; o; o >>= 1) qv += __shfl_xor(qv, o);
    float rstd = rsqrtf(qv * (1.0f / 64.0f) + 1e-5f);
    out[row * 64 + lane] = d * rstd * g[lane] + b[lane];
}

// ---------------------------------------------------------------- fused MLP + output layernorm (lean, l0)
__global__ __launch_bounds__(256) void k_mlp(
    const float* __restrict__ xm,
    const float* __restrict__ W1, const float* __restrict__ bb1,
    const float* __restrict__ W2, const float* __restrict__ bb2,
    const float* __restrict__ g, const float* __restrict__ b,
    float* __restrict__ out)
{
    __shared__ float As[64][65];
    __shared__ float W1s[64][65];
    __shared__ float W2s[64][65];
    int tid = threadIdx.x;
    int m0 = blockIdx.x * 64;
    #pragma unroll
    for (int it = 0; it < 16; ++it) {
        int idx = tid + it * 256;
        int r = idx >> 6, c = idx & 63;
        As[r][c]  = xm[(long)(m0 + r) * 64 + c];
        W1s[r][c] = W1[(long)r * 64 + c];
        W2s[r][c] = W2[(long)r * 64 + c];
    }
    __syncthreads();
    int tx = tid & 15, ty = tid >> 4;
    float acc[4][4] = {};
    #pragma unroll
    for (int k = 0; k < 64; ++k) {
        float a[4], w[4];
        #pragma unroll
        for (int i = 0; i < 4; ++i) a[i] = As[ty * 4 + i][k];
        #pragma unroll
        for (int j = 0; j < 4; ++j) w[j] = W1s[k][tx * 4 + j];
        #pragma unroll
        for (int i = 0; i < 4; ++i)
            #pragma unroll
            for (int j = 0; j < 4; ++j) acc[i][j] += a[i] * w[j];
    }
    __syncthreads();
    #pragma unroll
    for (int i = 0; i < 4; ++i)
        #pragma unroll
        for (int j = 0; j < 4; ++j)
            W1s[ty * 4 + i][tx * 4 + j] = gelu_exact(acc[i][j] + bb1[tx * 4 + j]);
    __syncthreads();
    float acc2[4][4] = {};
    #pragma unroll
    for (int k = 0; k < 64; ++k) {
        float a[4], w[4];
        #pragma unroll
        for (int i = 0; i < 4; ++i) a[i] = W1s[ty * 4 + i][k];
        #pragma unroll
        for (int j = 0; j < 4; ++j) w[j] = W2s[k][tx * 4 + j];
        #pragma unroll
        for (int i = 0; i < 4; ++i)
            #pragma unroll
            for (int j = 0; j < 4; ++j) acc2[i][j] += a[i] * w[j];
    }
    #pragma unroll
    for (int i = 0; i < 4; ++i) {
        float v[4];
        float s = 0.f;
        #pragma unroll
        for (int j = 0; j < 4; ++j) {
            v[j] = acc2[i][j] + bb2[tx * 4 + j] + As[ty * 4 + i][tx * 4 + j];
            s += v[j];
        }
        #pragma unroll
        for (int o = 1; o < 16; o <<= 1) s += __shfl_xor(s, o);
        float m = s * (1.0f / 64.0f);
        float q = 0.f;
        #pragma unroll
        for (int j = 0; j < 4; ++j) { float d = v[j] - m; q += d * d; }
        #pragma unroll
        for (int o = 1; o < 16; o <<= 1) q += __shfl_xor(q, o);
        float rstd = rsqrtf(q * (1.0f / 64.0f) + 1e-5f);
        long row = m0 + ty * 4 + i;
        #pragma unroll
        for (int j = 0; j < 4; ++j) {
            int col = tx * 4 + j;
            out[row * 64 + col] = (v[j] - m) * rstd * g[col] + b[col];
        }
    }
}

// ---------------------------------------------------------------- l1: avcat residual + input-LN + MLP + output-LN
// v = xn + avcat + boutv; xm = LN(v,gin,bin); out = LN(xm + gelu(xm@W1+bb1)@W2 + bb2, gout, bln)
__global__ __launch_bounds__(256) void k_mlp_av(
    const float* __restrict__ xn, const float* __restrict__ avcat,
    const float* __restrict__ boutv,
    const float* __restrict__ gin, const float* __restrict__ bin,
    const float* __restrict__ W1, const float* __restrict__ bb1,
    const float* __restrict__ W2, const float* __restrict__ bb2,
    const float* __restrict__ gout, const float* __restrict__ bln,
    float* __restrict__ out)
{
    __shared__ float As[64][65];
    __shared__ float W1s[64][65];
    __shared__ float W2s[64][65];
    int tid = threadIdx.x;
    int m0 = blockIdx.x * 64;
    #pragma unroll
    for (int it = 0; it < 16; ++it) {
        int idx = tid + it * 256;
        int r = idx >> 6, c = idx & 63;
        long row = m0 + r;
        int n = (int)(row & 4095), bb = (int)(row >> 12);
        As[r][c]  = xn[row * 64 + c] + avcat[(long)n * 128 + bb * 64 + c] + boutv[c];
        W1s[r][c] = W1[(long)r * 64 + c];
        W2s[r][c] = W2[(long)r * 64 + c];
    }
    __syncthreads();
    int tx = tid & 15, ty = tid >> 4;
    // input layernorm in LDS (16-lane row groups)
    #pragma unroll
    for (int i = 0; i < 4; ++i) {
        float vv[4];
        float s = 0.f;
        #pragma unroll
        for (int j = 0; j < 4; ++j) { vv[j] = As[ty * 4 + i][tx * 4 + j]; s += vv[j]; }
        #pragma unroll
        for (int o = 1; o < 16; o <<= 1) s += __shfl_xor(s, o);
        float m = s * (1.0f / 64.0f);
        float qv = 0.f;
        #pragma unroll
        for (int j = 0; j < 4; ++j) { float d = vv[j] - m; qv += d * d; }
        #pragma unroll
        for (int o = 1; o < 16; o <<= 1) qv += __shfl_xor(qv, o);
        float rstd = rsqrtf(qv * (1.0f / 64.0f) + 1e-5f);
        #pragma unroll
        for (int j = 0; j < 4; ++j) {
            int col = tx * 4 + j;
            As[ty * 4 + i][col] = (vv[j] - m) * rstd * gin[col] + bin[col];
        }
    }
    __syncthreads();
    // gemm1: h = gelu(xm @ W1 + bb1)
    float acc[4][4] = {};
    #pragma unroll
    for (int k = 0; k < 64; ++k) {
        float a[4], w[4];
        #pragma unroll
        for (int i = 0; i < 4; ++i) a[i] = As[ty * 4 + i][k];
        #pragma unroll
        for (int j = 0; j < 4; ++j) w[j] = W1s[k][tx * 4 + j];
        #pragma unroll
        for (int i = 0; i < 4; ++i)
            #pragma unroll
            for (int j = 0; j < 4; ++j) acc[i][j] += a[i] * w[j];
    }
    __syncthreads();
    #pragma unroll
    for (int i = 0; i < 4; ++i)
        #pragma unroll
        for (int j = 0; j < 4; ++j)
            W1s[ty * 4 + i][tx * 4 + j] = gelu_exact(acc[i][j] + bb1[tx * 4 + j]);
    __syncthreads();
    // gemm2 + residual + output layernorm
    float acc2[4][4] = {};
    #pragma unroll
    for (int k = 0; k < 64; ++k) {
        float a[4], w[4];
        #pragma unroll
        for (int i = 0; i < 4; ++i) a[i] = W1s[ty * 4 + i][k];
        #pragma unroll
        for (int j = 0; j < 4; ++j) w[j] = W2s[k][tx * 4 + j];
        #pragma unroll
        for (int i = 0; i < 4; ++i)
            #pragma unroll
            for (int j = 0; j < 4; ++j) acc2[i][j] += a[i] * w[j];
    }
    #pragma unroll
    for (int i = 0; i < 4; ++i) {
        float v[4];
        float s = 0.f;
        #pragma unroll
        for (int j = 0; j < 4; ++j) {
            v[j] = acc2[i][j] + bb2[tx * 4 + j] + As[ty * 4 + i][tx * 4 + j];
            s += v[j];
        }
        #pragma unroll
        for (int o = 1; o < 16; o <<= 1) s += __shfl_xor(s, o);
        float m = s * (1.0f / 64.0f);
        float qv = 0.f;
        #pragma unroll
        for (int j = 0; j < 4; ++j) { float d = v[j] - m; qv += d * d; }
        #pragma unroll
        for (int o = 1; o < 16; o <<= 1) qv += __shfl_xor(qv, o);
        float rstd = rsqrtf(qv * (1.0f / 64.0f) + 1e-5f);
        long row = m0 + ty * 4 + i;
        #pragma unroll
        for (int j = 0; j < 4; ++j) {
            int col = tx * 4 + j;
            out[row * 64 + col] = (v[j] - m) * rstd * gout[col] + bln[col];
        }
    }
}

// ---------------------------------------------------------------- launch
extern "C" void kernel_launch(void* const* d_in, const int* in_sizes, int n_in,
                              void* d_out, int out_size, void* d_ws, size_t ws_size,
                              hipStream_t stream)
{
    const float* embed = (const float*)d_in[0];
    const float* Aadj  = (const float*)d_in[1];
    const float* g1    = (const float*)d_in[2];
    const float* b1    = (const float*)d_in[3];
    const float* Wqkv  = (const float*)d_in[4];
    const float* Wout  = (const float*)d_in[5];
    const float* bout  = (const float*)d_in[6];
    const float* g2    = (const float*)d_in[7];
    const float* b2    = (const float*)d_in[8];
    const float* W1    = (const float*)d_in[9];
    const float* bb1   = (const float*)d_in[10];
    const float* W2    = (const float*)d_in[11];
    const float* bb2   = (const float*)d_in[12];
    const float* gf    = (const float*)d_in[13];
    const float* bff   = (const float*)d_in[14];

    // output regions (fp32): [x 524288 | attn 16777216 | ds 16777216]
    float* ox    = (float*)d_out;            // final x
    float* attnb = ox + 524288;              // attn output; l0 flash scratch; l1 strided bf16 dots
    float* dsb   = attnb + 16777216;         // ds output

    if (ws_size < (10ull << 20)) {           // diagnostic guard
        k_zero<<<133120, 256, 0, stream>>>(ox, 34078720l);
        return;
    }

    // workspace layout (non-aliased, 9.05 MB; mask +2 MB if available)
    char* ws = (char*)d_ws;
    float*          xn     = (float*)(ws + (0l << 20));            // 2 MB [8192,64]
    unsigned short* q      = (unsigned short*)(ws + (2l << 20));   // 2 MB [4096,256] bf16
    unsigned short* kmat   = (unsigned short*)(ws + (4l << 20));   // 2 MB [4096,256] bf16
    unsigned short* vwt    = (unsigned short*)(ws + (6l << 20));   // 1 MB [128,4096] bf16
    float*          OA     = (float*)(ws + (7l << 20));            // 2 MB [4096,128] l1 avcat accum
    float*          Wfold  = (float*)(ws + (9l << 20));            // 32 KB [2][64,64]
    unsigned long long* mask = (ws_size >= (12ull << 20))
        ? (unsigned long long*)(ws + (10l << 20)) : nullptr;       // 2 MB [4096,64]

    unsigned short* part   = (unsigned short*)attnb;               // 16 MB flash partials (l0)
    float*          fstats = attnb + 4194304;                      // 512 KB flash stats (l0)
    unsigned short* dots_b = (unsigned short*)attnb;               // l1: [4096] rows, stride 8192

    // -------- prologue: maskpack | Wfold(both) | LN(embed) | zero OA --------
    k_prologue<<<8224, 256, 0, stream>>>(Aadj, mask, Wqkv, Wout, Wfold,
                                         embed, g1, b1, xn, OA);

    // -------- layer 0 (attn/ds are scratch -> parts flash) --------
    k_qkx<<<dim3(64, 10), 256, 0, stream>>>(xn, Wqkv, Wfold, q, kmat, vwt);
    k_flash<<<dim3(32, NG), 256, 0, stream>>>(q, kmat, vwt, mask, Aadj, part, fstats);
    k_avres_ln_c<<<2048, 256, 0, stream>>>(xn, part, fstats, bout, g2, b2, xn);  // xm in place
    k_mlp<<<128, 256, 0, stream>>>(xn, W1, bb1, W2, bb2,
                                   g1 + 64, b1 + 64, xn);                        // -> next xn

    // -------- layer 1 (attn/ds are required fp32 outputs) --------
    k_qkx<<<dim3(64, 10), 256, 0, stream>>>(xn, Wqkv + 64 * 768, Wfold + 4096, q, kmat, vwt);
    k_mfma_nt<<<dim3(32, 32), 256, 0, stream>>>(q, kmat, dots_b, 8192, 256, 0.125f);
    k_softmax_io<<<4096, 256, 0, stream>>>(dots_b, Aadj, mask, attnb, dsb);
    k_mfma_splitk<<<dim3(32, 8), 256, 0, stream>>>(attnb, vwt, OA);
    k_mlp_av<<<128, 256, 0, stream>>>(xn, OA, bout + 64, g2 + 64, b2 + 64,
                                      W1 + 4096, bb1 + 64, W2 + 4096, bb2 + 64,
                                      gf, bff, ox);                              // final LN -> out
}

// Round 8
// 461.427 us; speedup vs baseline: 1.0405x; 1.0079x over previous
//
#include <hip/hip_runtime.h>
#include <hip/hip_bf16.h>
#include <math.h>

typedef __attribute__((ext_vector_type(8))) short short8;
typedef __attribute__((ext_vector_type(4))) float f32x4;

#define NG 16   // flash j-groups

__device__ __forceinline__ unsigned short f2bf(float x) {
    __hip_bfloat16 b = __float2bfloat16(x);
    return *reinterpret_cast<unsigned short*>(&b);
}
__device__ __forceinline__ float bf2f(unsigned short u) {
    unsigned int t = ((unsigned int)u) << 16;
    float f;
    __builtin_memcpy(&f, &t, 4);
    return f;
}
__device__ __forceinline__ float gelu_exact(float x) {
    return 0.5f * x * (1.0f + erff(x * 0.70710678118654752f));
}

// ---------------------------------------------------------------- zero (diagnostic guard only)
__global__ __launch_bounds__(256) void k_zero(float* __restrict__ p, long n)
{
    long i = (long)blockIdx.x * 256 + threadIdx.x;
    if (i < n) p[i] = 0.f;
}

// ---------------------------------------------------------------- prologue: maskpack | wfold | LN(embed) | zero OA
__global__ __launch_bounds__(256) void k_prologue(
    const float* __restrict__ Aadj, unsigned long long* __restrict__ mask,
    const float* __restrict__ Wqkv, const float* __restrict__ Wout,
    float* __restrict__ Wfold,
    const float* __restrict__ embed, const float* __restrict__ g1,
    const float* __restrict__ b1, float* __restrict__ xn,
    float* __restrict__ OA)
{
    int bx = blockIdx.x, tid = threadIdx.x;
    if (bx < 4096) {                      // ---- mask pack
        if (!mask) return;
        int row = bx;
        int wave = tid >> 6, lane = tid & 63;
        for (int w = wave; w < 64; w += 4) {
            float a = Aadj[(long)row * 4096 + w * 64 + lane];
            unsigned long long m = __ballot(a > 0.f);
            if (lane == 0) mask[(long)row * 64 + w] = m;
        }
    } else if (bx < 4128) {               // ---- Wfold = Wqkv_v @ Wout [2][64,64]
        int bid = bx - 4096;
        int l = bid >> 4;
        int idx = (bid & 15) * 256 + tid;
        int c = idx >> 6, d = idx & 63;
        const float* Wq = Wqkv + (long)l * 64 * 768;
        const float* Wo = Wout + (long)l * 256 * 64;
        float a = 0.f;
        for (int k = 0; k < 256; ++k)
            a += Wq[c * 768 + 512 + k] * Wo[k * 64 + d];
        Wfold[l * 4096 + idx] = a;
    } else if (bx < 6176) {               // ---- layernorm(embed) -> xn
        int wave = tid >> 6, lane = tid & 63;
        long row = (long)(bx - 4128) * 4 + wave;
        float v = embed[row * 64 + lane];
        float s = v;
        #pragma unroll
        for (int o = 32; o; o >>= 1) s += __shfl_xor(s, o);
        float m = s * (1.0f / 64.0f);
        float d = v - m;
        float q = d * d;
        #pragma unroll
        for (int o = 32; o; o >>= 1) q += __shfl_xor(q, o);
        float rstd = rsqrtf(q * (1.0f / 64.0f) + 1e-5f);
        xn[row * 64 + lane] = d * rstd * g1[lane] + b1[lane];
    } else {                              // ---- zero OA accum (2 MB, used by l1 splitk)
        long i = (long)(bx - 6176) * 256 + tid;
        if (i < 524288) OA[i] = 0.f;
    }
}

// ---------------------------------------------------------------- merged q,k gemm + vWT gemm
// grid (64, 10): y<8 -> qk tile (n0=y*64); y>=8 -> vWT batch b=y-8
__global__ __launch_bounds__(256) void k_qkx(
    const float* __restrict__ xn, const float* __restrict__ W,
    const float* __restrict__ Wfold,
    unsigned short* __restrict__ q, unsigned short* __restrict__ kmat,
    unsigned short* __restrict__ vWT)
{
    __shared__ float As[64][65];
    __shared__ float Ws[64][65];
    int tid = threadIdx.x;
    int by = blockIdx.y;
    int tx = tid & 15, ty = tid >> 4;
    if (by < 8) {
        int m0 = blockIdx.x * 64, n0 = by * 64;
        #pragma unroll
        for (int it = 0; it < 16; ++it) {
            int idx = tid + it * 256;
            int r = idx >> 6, c = idx & 63;
            As[r][c] = xn[(long)(m0 + r) * 64 + c];
            Ws[r][c] = W[(long)r * 768 + n0 + c];
        }
        __syncthreads();
        float acc[4][4] = {};
        #pragma unroll
        for (int k = 0; k < 64; ++k) {
            float a[4], w[4];
            #pragma unroll
            for (int i = 0; i < 4; ++i) a[i] = As[ty * 4 + i][k];
            #pragma unroll
            for (int j = 0; j < 4; ++j) w[j] = Ws[k][tx * 4 + j];
            #pragma unroll
            for (int i = 0; i < 4; ++i)
                #pragma unroll
                for (int j = 0; j < 4; ++j) acc[i][j] += a[i] * w[j];
        }
        #pragma unroll
        for (int i = 0; i < 4; ++i) {
            long row = m0 + ty * 4 + i;
            #pragma unroll
            for (int j = 0; j < 4; ++j) {
                int col = n0 + tx * 4 + j;
                if (col < 256) q[row * 256 + col] = f2bf(acc[i][j]);
                else           kmat[row * 256 + (col - 256)] = f2bf(acc[i][j]);
            }
        }
    } else {
        int n0 = blockIdx.x * 64, b = by - 8;
        #pragma unroll
        for (int it = 0; it < 16; ++it) {
            int idx = tid + it * 256;
            int r = idx >> 6, c = idx & 63;
            As[r][c] = xn[((long)b * 4096 + n0 + r) * 64 + c];
            Ws[r][c] = Wfold[r * 64 + c];
        }
        __syncthreads();
        float acc[4][4] = {};
        #pragma unroll
        for (int k = 0; k < 64; ++k) {
            float a[4], w[4];
            #pragma unroll
            for (int i = 0; i < 4; ++i) a[i] = As[ty * 4 + i][k];
            #pragma unroll
            for (int j = 0; j < 4; ++j) w[j] = Ws[k][tx * 4 + j];
            #pragma unroll
            for (int i = 0; i < 4; ++i)
                #pragma unroll
                for (int j = 0; j < 4; ++j) acc[i][j] += a[i] * w[j];
        }
        #pragma unroll
        for (int i = 0; i < 4; ++i)
            #pragma unroll
            for (int j = 0; j < 4; ++j)
                vWT[((long)b * 64 + tx * 4 + j) * 4096 + n0 + ty * 4 + i] = f2bf(acc[i][j]);
    }
}

// ---------------------------------------------------------------- flash attention (layer 0), parts/stats
__global__ __launch_bounds__(256) void k_flash(
    const unsigned short* __restrict__ q, const unsigned short* __restrict__ kmat,
    const unsigned short* __restrict__ vwt,
    const unsigned long long* __restrict__ mask, const float* __restrict__ Aadj,
    unsigned short* __restrict__ part,   // [NG][4096][128] bf16
    float* __restrict__ stats)           // [NG][4096][2] (m, s)
{
    __shared__ __align__(16) unsigned short Qs[128 * 64];
    __shared__ __align__(16) unsigned short Ks[128 * 64];
    __shared__ __align__(16) unsigned short Ps[128 * 128];
    int tid = threadIdx.x;
    int lane = tid & 63, wq = tid >> 6;
    int fr = lane & 15, quad = lane >> 4;
    int m0 = blockIdx.x * 128;
    int g  = blockIdx.y;

    f32x4 accO[2][8];
    #pragma unroll
    for (int i = 0; i < 2; ++i)
        #pragma unroll
        for (int j = 0; j < 8; ++j) accO[i][j] = (f32x4){0.f, 0.f, 0.f, 0.f};
    float m_run[2] = {-1e30f, -1e30f};
    float s_run[2] = {0.f, 0.f};

    for (int jt = 0; jt < 2; ++jt) {
        int jb = g * 256 + jt * 128;
        f32x4 accS[8][2];
        #pragma unroll
        for (int i = 0; i < 8; ++i)
            #pragma unroll
            for (int n = 0; n < 2; ++n) accS[i][n] = (f32x4){0.f, 0.f, 0.f, 0.f};
        for (int k0 = 0; k0 < 256; k0 += 64) {
            #pragma unroll
            for (int it = 0; it < 4; ++it) {
                int idx = tid + it * 256;
                int r = idx >> 3, c8 = (idx & 7) * 8;
                *(short8*)&Qs[idx * 8] = *(const short8*)(q    + (long)(m0 + r) * 256 + k0 + c8);
                *(short8*)&Ks[idx * 8] = *(const short8*)(kmat + (long)(jb + r) * 256 + k0 + c8);
            }
            __syncthreads();
            #pragma unroll
            for (int ks = 0; ks < 2; ++ks) {
                short8 ka[8], qb[2];
                #pragma unroll
                for (int i = 0; i < 8; ++i)
                    ka[i] = *(const short8*)&Ks[(i * 16 + fr) * 64 + ks * 32 + quad * 8];
                #pragma unroll
                for (int n = 0; n < 2; ++n)
                    qb[n] = *(const short8*)&Qs[(wq * 32 + n * 16 + fr) * 64 + ks * 32 + quad * 8];
                #pragma unroll
                for (int i = 0; i < 8; ++i)
                    #pragma unroll
                    for (int n = 0; n < 2; ++n)
                        accS[i][n] = __builtin_amdgcn_mfma_f32_16x16x32_bf16(
                            ka[i], qb[n], accS[i][n], 0, 0, 0);
            }
            __syncthreads();
        }
        float al[2];
        #pragma unroll
        for (int n = 0; n < 2; ++n) {
            int qrow = m0 + wq * 32 + n * 16 + fr;
            unsigned long long mw0 = 0, mw1 = 0;
            if (mask) {
                mw0 = mask[(long)qrow * 64 + (jb >> 6)];
                mw1 = mask[(long)qrow * 64 + (jb >> 6) + 1];
            }
            float tm = -1e30f;
            #pragma unroll
            for (int i = 0; i < 8; ++i) {
                #pragma unroll
                for (int r = 0; r < 4; ++r) {
                    int jl = i * 16 + quad * 4 + r;
                    float v = accS[i][n][r] * 0.125f;
                    bool keep = mask ? (((jl < 64 ? (mw0 >> jl) : (mw1 >> (jl - 64))) & 1ull) != 0)
                                     : (Aadj[(long)qrow * 4096 + jb + jl] > 0.f);
                    v = keep ? v : -1e30f;
                    if (jb + jl == qrow) v = 1.0f;
                    accS[i][n][r] = v;
                    tm = fmaxf(tm, v);
                }
            }
            tm = fmaxf(tm, __shfl_xor(tm, 16));
            tm = fmaxf(tm, __shfl_xor(tm, 32));
            float mnew = fmaxf(fmaxf(m_run[n], tm), -1e20f);
            al[n] = __expf(m_run[n] - mnew);
            m_run[n] = mnew;
            float ts = 0.f;
            int qrl = wq * 32 + n * 16 + fr;
            #pragma unroll
            for (int i = 0; i < 8; ++i) {
                float p0 = __expf(accS[i][n][0] - mnew);
                float p1 = __expf(accS[i][n][1] - mnew);
                float p2 = __expf(accS[i][n][2] - mnew);
                float p3 = __expf(accS[i][n][3] - mnew);
                ts += (p0 + p1) + (p2 + p3);
                unsigned int lo = (unsigned int)f2bf(p0) | ((unsigned int)f2bf(p1) << 16);
                unsigned int hi = (unsigned int)f2bf(p2) | ((unsigned int)f2bf(p3) << 16);
                int u = (qrl * 128 + i * 16 + quad * 4) ^ ((fr & 7) << 3);
                *(uint2*)&Ps[u] = make_uint2(lo, hi);
            }
            ts += __shfl_xor(ts, 16);
            ts += __shfl_xor(ts, 32);
            s_run[n] = s_run[n] * al[n] + ts;
        }
        #pragma unroll
        for (int ii = 0; ii < 2; ++ii) {
            float av[4];
            #pragma unroll
            for (int r = 0; r < 4; ++r) av[r] = __shfl(al[ii], quad * 4 + r);
            #pragma unroll
            for (int nn = 0; nn < 8; ++nn)
                #pragma unroll
                for (int r = 0; r < 4; ++r) accO[ii][nn][r] *= av[r];
        }
        #pragma unroll
        for (int it = 0; it < 4; ++it) {
            int idx = tid + it * 256;
            int r = idx >> 3, c8 = (idx & 7) * 8;
            *(short8*)&Qs[idx * 8] = *(const short8*)(vwt + (long)r * 4096 + jb + c8);
            *(short8*)&Ks[idx * 8] = *(const short8*)(vwt + (long)r * 4096 + jb + 64 + c8);
        }
        __syncthreads();
        #pragma unroll
        for (int ks4 = 0; ks4 < 4; ++ks4) {
            const unsigned short* buf = (ks4 < 2) ? Qs : Ks;
            int ksl = ks4 & 1;
            short8 pa[2], vb[8];
            #pragma unroll
            for (int ii = 0; ii < 2; ++ii) {
                int u = ((wq * 32 + ii * 16 + fr) * 128 + ks4 * 32 + quad * 8) ^ ((fr & 7) << 3);
                pa[ii] = *(const short8*)&Ps[u];
            }
            #pragma unroll
            for (int nn = 0; nn < 8; ++nn)
                vb[nn] = *(const short8*)&buf[(nn * 16 + fr) * 64 + ksl * 32 + quad * 8];
            #pragma unroll
            for (int ii = 0; ii < 2; ++ii)
                #pragma unroll
                for (int nn = 0; nn < 8; ++nn)
                    accO[ii][nn] = __builtin_amdgcn_mfma_f32_16x16x32_bf16(
                        pa[ii], vb[nn], accO[ii][nn], 0, 0, 0);
        }
        __syncthreads();
    }
    #pragma unroll
    for (int ii = 0; ii < 2; ++ii) {
        #pragma unroll
        for (int nn = 0; nn < 8; ++nn) {
            int ch = nn * 16 + fr;
            long rowb = m0 + wq * 32 + ii * 16 + quad * 4;
            #pragma unroll
            for (int r = 0; r < 4; ++r)
                part[((long)g * 4096 + rowb + r) * 128 + ch] = f2bf(accO[ii][nn][r]);
        }
    }
    if (quad == 0) {
        #pragma unroll
        for (int n = 0; n < 2; ++n) {
            int qrow = m0 + wq * 32 + n * 16 + fr;
            stats[((long)g * 4096 + qrow) * 2]     = m_run[n];
            stats[((long)g * 4096 + qrow) * 2 + 1] = s_run[n];
        }
    }
}

// ---------------------------------------------------------------- dots GEMM (NT, bf16 in, bf16 out, strided ld)
__global__ __launch_bounds__(256) void k_mfma_nt(
    const unsigned short* __restrict__ A, const unsigned short* __restrict__ B,
    unsigned short* __restrict__ Cb, int ld, int K, float scale)
{
    __shared__ __align__(16) unsigned short As[128 * 64];
    __shared__ __align__(16) unsigned short Bs[128 * 64];
    int tid = threadIdx.x;
    int lane = tid & 63, wave = tid >> 6;
    long m0 = (long)blockIdx.x * 128, n0 = (long)blockIdx.y * 128;
    const unsigned short* Ag = A + m0 * K;
    const unsigned short* Bg = B + n0 * K;
    int wm = (wave & 1) * 64, wn = (wave >> 1) * 64;
    int fr = lane & 15, quad = lane >> 4;

    f32x4 acc[4][4];
    #pragma unroll
    for (int i = 0; i < 4; ++i)
        #pragma unroll
        for (int j = 0; j < 4; ++j) acc[i][j] = (f32x4){0.f, 0.f, 0.f, 0.f};

    for (int k0 = 0; k0 < K; k0 += 64) {
        #pragma unroll
        for (int it = 0; it < 4; ++it) {
            int c = tid + it * 256;
            int r = c >> 3, col = (c & 7) * 8;
            *(short8*)&As[c * 8] = *(const short8*)(Ag + (long)r * K + k0 + col);
            *(short8*)&Bs[c * 8] = *(const short8*)(Bg + (long)r * K + k0 + col);
        }
        __syncthreads();
        #pragma unroll
        for (int ks = 0; ks < 2; ++ks) {
            short8 af[4], bfr[4];
            #pragma unroll
            for (int i = 0; i < 4; ++i) {
                af[i]  = *(const short8*)&As[(wm + i * 16 + fr) * 64 + ks * 32 + quad * 8];
                bfr[i] = *(const short8*)&Bs[(wn + i * 16 + fr) * 64 + ks * 32 + quad * 8];
            }
            #pragma unroll
            for (int i = 0; i < 4; ++i)
                #pragma unroll
                for (int j = 0; j < 4; ++j)
                    acc[i][j] = __builtin_amdgcn_mfma_f32_16x16x32_bf16(
                        af[i], bfr[j], acc[i][j], 0, 0, 0);
        }
        __syncthreads();
    }
    #pragma unroll
    for (int i = 0; i < 4; ++i) {
        #pragma unroll
        for (int j = 0; j < 4; ++j) {
            long col = n0 + wn + j * 16 + fr;
            long rowb = m0 + wm + i * 16 + quad * 4;
            #pragma unroll
            for (int r = 0; r < 4; ++r)
                Cb[(rowb + r) * ld + col] = f2bf(acc[i][j][r] * scale);
        }
    }
}

// ---------------------------------------------------------------- block reduce helpers
__device__ __forceinline__ float block_max(float v, float* red, int lane, int wave) {
    #pragma unroll
    for (int o = 32; o; o >>= 1) v = fmaxf(v, __shfl_xor(v, o));
    if (lane == 0) red[wave] = v;
    __syncthreads();
    v = fmaxf(fmaxf(red[0], red[1]), fmaxf(red[2], red[3]));
    __syncthreads();
    return v;
}
__device__ __forceinline__ float block_sum(float v, float* red, int lane, int wave) {
    #pragma unroll
    for (int o = 32; o; o >>= 1) v += __shfl_xor(v, o);
    if (lane == 0) red[wave] = v;
    __syncthreads();
    v = red[0] + red[1] + red[2] + red[3];
    __syncthreads();
    return v;
}

// ---------------------------------------------------------------- dual softmax, bf16 strided in -> fp32 in-place
__global__ __launch_bounds__(256) void k_softmax_io(
    const unsigned short* __restrict__ dots_b, const float* __restrict__ Aadj,
    const unsigned long long* __restrict__ mask,
    float* __restrict__ attn, float* __restrict__ ds)
{
    __shared__ float red[4];
    __shared__ unsigned long long msk[64];
    int row = blockIdx.x, tid = threadIdx.x;
    int lane = tid & 63, wave = tid >> 6;
    if (mask) {
        if (tid < 64) msk[tid] = mask[(long)row * 64 + tid];
        __syncthreads();
    }
    const unsigned short* drow = dots_b + (long)row * 8192 + tid * 16;
    short8 dv0 = *(const short8*)drow;
    short8 dv1 = *(const short8*)(drow + 8);
    unsigned long long mword = mask ? msk[tid >> 2] : 0ull;
    int bitbase = (tid & 3) * 16;
    float d[16], mv[16];
    float mmax = -1e30f, umax = -1e30f;
    #pragma unroll
    for (int i = 0; i < 16; ++i) {
        unsigned short u = (unsigned short)(i < 8 ? dv0[i] : dv1[i - 8]);
        float dvf = bf2f(u);
        int j = tid * 16 + i;
        d[i] = dvf;
        bool keep = mask ? ((mword >> (bitbase + i)) & 1ull)
                         : (Aadj[(long)row * 4096 + j] > 0.f);
        float m = keep ? dvf : -1e30f;
        if (j == row) m = 1.0f;
        mv[i] = m;
        mmax = fmaxf(mmax, m);
        umax = fmaxf(umax, dvf);
    }
    float M1 = block_max(mmax, red, lane, wave);
    float s1 = 0.f;
    #pragma unroll
    for (int i = 0; i < 16; ++i) { float e = __expf(mv[i] - M1); mv[i] = e; s1 += e; }
    s1 = block_sum(s1, red, lane, wave);
    float inv1 = 1.0f / s1;
    float* arow = attn + (long)row * 4096 + tid * 16;
    *(float4*)(arow + 0)  = make_float4(mv[0]*inv1, mv[1]*inv1, mv[2]*inv1, mv[3]*inv1);
    *(float4*)(arow + 4)  = make_float4(mv[4]*inv1, mv[5]*inv1, mv[6]*inv1, mv[7]*inv1);
    *(float4*)(arow + 8)  = make_float4(mv[8]*inv1, mv[9]*inv1, mv[10]*inv1, mv[11]*inv1);
    *(float4*)(arow + 12) = make_float4(mv[12]*inv1, mv[13]*inv1, mv[14]*inv1, mv[15]*inv1);

    float M2 = block_max(umax, red, lane, wave);
    float s2 = 0.f;
    #pragma unroll
    for (int i = 0; i < 16; ++i) { float e = __expf(d[i] - M2); d[i] = e; s2 += e; }
    s2 = block_sum(s2, red, lane, wave);
    float inv2 = 1.0f / s2;
    float* srow = ds + (long)row * 4096 + tid * 16;
    *(float4*)(srow + 0)  = make_float4(d[0]*inv2, d[1]*inv2, d[2]*inv2, d[3]*inv2);
    *(float4*)(srow + 4)  = make_float4(d[4]*inv2, d[5]*inv2, d[6]*inv2, d[7]*inv2);
    *(float4*)(srow + 8)  = make_float4(d[8]*inv2, d[9]*inv2, d[10]*inv2, d[11]*inv2);
    *(float4*)(srow + 12) = make_float4(d[12]*inv2, d[13]*inv2, d[14]*inv2, d[15]*inv2);
}

// ---------------------------------------------------------------- attn@vWT split-K GEMM (fp32 A)
__global__ __launch_bounds__(256) void k_mfma_splitk(
    const float* __restrict__ A, const unsigned short* __restrict__ B,
    float* __restrict__ C)
{
    __shared__ __align__(16) unsigned short As[128 * 64];
    __shared__ __align__(16) unsigned short Bs[128 * 64];
    const int K = 4096, N = 128;
    int tid = threadIdx.x;
    int lane = tid & 63, wave = tid >> 6;
    long m0 = (long)blockIdx.x * 128;
    int k0base = blockIdx.y * 512;
    const float* Ag = A + m0 * K;
    int wm = (wave & 1) * 64, wn = (wave >> 1) * 64;
    int fr = lane & 15, quad = lane >> 4;

    f32x4 acc[4][4];
    #pragma unroll
    for (int i = 0; i < 4; ++i)
        #pragma unroll
        for (int j = 0; j < 4; ++j) acc[i][j] = (f32x4){0.f, 0.f, 0.f, 0.f};

    for (int k0 = k0base; k0 < k0base + 512; k0 += 64) {
        #pragma unroll
        for (int it = 0; it < 4; ++it) {
            int c = tid + it * 256;
            int r = c >> 3, col = (c & 7) * 8;
            float4 f0 = *(const float4*)(Ag + (long)r * K + k0 + col);
            float4 f1 = *(const float4*)(Ag + (long)r * K + k0 + col + 4);
            short8 s;
            s[0] = (short)f2bf(f0.x); s[1] = (short)f2bf(f0.y);
            s[2] = (short)f2bf(f0.z); s[3] = (short)f2bf(f0.w);
            s[4] = (short)f2bf(f1.x); s[5] = (short)f2bf(f1.y);
            s[6] = (short)f2bf(f1.z); s[7] = (short)f2bf(f1.w);
            *(short8*)&As[c * 8] = s;
            *(short8*)&Bs[c * 8] = *(const short8*)(B + (long)r * K + k0 + col);
        }
        __syncthreads();
        #pragma unroll
        for (int ks = 0; ks < 2; ++ks) {
            short8 af[4], bfr[4];
            #pragma unroll
            for (int i = 0; i < 4; ++i) {
                af[i]  = *(const short8*)&As[(wm + i * 16 + fr) * 64 + ks * 32 + quad * 8];
                bfr[i] = *(const short8*)&Bs[(wn + i * 16 + fr) * 64 + ks * 32 + quad * 8];
            }
            #pragma unroll
            for (int i = 0; i < 4; ++i)
                #pragma unroll
                for (int j = 0; j < 4; ++j)
                    acc[i][j] = __builtin_amdgcn_mfma_f32_16x16x32_bf16(
                        af[i], bfr[j], acc[i][j], 0, 0, 0);
        }
        __syncthreads();
    }
    #pragma unroll
    for (int i = 0; i < 4; ++i) {
        #pragma unroll
        for (int j = 0; j < 4; ++j) {
            long col = wn + j * 16 + fr;
            long rowb = m0 + wm + i * 16 + quad * 4;
            #pragma unroll
            for (int r = 0; r < 4; ++r)
                atomicAdd(&C[(rowb + r) * N + col], acc[i][j][r]);
        }
    }
}

// ---------------------------------------------------------------- l0: flash-combine + residual + LN + MLP + LN
// v = xn + combine(part,fstats) + boutv; xm = LN(v,gin,bin);
// out = LN(xm + gelu(xm@W1+bb1)@W2 + bb2, gout, bln)     (out may alias xn)
__global__ __launch_bounds__(256) void k_mlp_c(
    const float* __restrict__ xn, const unsigned short* __restrict__ part,
    const float* __restrict__ fstats, const float* __restrict__ boutv,
    const float* __restrict__ gin, const float* __restrict__ bin,
    const float* __restrict__ W1, const float* __restrict__ bb1,
    const float* __restrict__ W2, const float* __restrict__ bb2,
    const float* __restrict__ gout, const float* __restrict__ bln,
    float* __restrict__ out)
{
    __shared__ float As[64][65];
    __shared__ float W1s[64][65];
    __shared__ float W2s[64][65];
    __shared__ float wg[64][NG + 1];
    int tid = threadIdx.x;
    int m0 = blockIdx.x * 64;
    // per-row combine weights (w[g] * inv_total) -- 64 threads
    if (tid < 64) {
        int n = (m0 + tid) & 4095;
        float mg[NG], sg[NG];
        float mx = -1e30f;
        #pragma unroll
        for (int g = 0; g < NG; ++g) {
            mg[g] = fstats[((long)g * 4096 + n) * 2];
            sg[g] = fstats[((long)g * 4096 + n) * 2 + 1];
            mx = fmaxf(mx, mg[g]);
        }
        float stot = 0.f;
        float w[NG];
        #pragma unroll
        for (int g = 0; g < NG; ++g) { w[g] = __expf(mg[g] - mx); stot += w[g] * sg[g]; }
        float inv = 1.0f / stot;
        #pragma unroll
        for (int g = 0; g < NG; ++g) wg[tid][g] = w[g] * inv;
    }
    // stage weights
    #pragma unroll
    for (int it = 0; it < 16; ++it) {
        int idx = tid + it * 256;
        int r = idx >> 6, c = idx & 63;
        W1s[r][c] = W1[(long)r * 64 + c];
        W2s[r][c] = W2[(long)r * 64 + c];
    }
    __syncthreads();
    // vectorized combine + residual -> As   (thread = (row, 16-col chunk))
    {
        int r = tid >> 2, c0 = (tid & 3) * 16;
        long row = m0 + r;
        int n = (int)(row & 4095), bb = (int)(row >> 12);
        float v[16];
        #pragma unroll
        for (int k = 0; k < 16; ++k) v[k] = xn[row * 64 + c0 + k] + boutv[c0 + k];
        for (int g = 0; g < NG; ++g) {
            const unsigned short* pp = part + ((long)g * 4096 + n) * 128 + bb * 64 + c0;
            short8 p0 = *(const short8*)pp;
            short8 p1 = *(const short8*)(pp + 8);
            float w = wg[r][g];
            #pragma unroll
            for (int k = 0; k < 8; ++k) {
                v[k]     += w * bf2f((unsigned short)p0[k]);
                v[8 + k] += w * bf2f((unsigned short)p1[k]);
            }
        }
        #pragma unroll
        for (int k = 0; k < 16; ++k) As[r][c0 + k] = v[k];
    }
    __syncthreads();
    int tx = tid & 15, ty = tid >> 4;
    // input layernorm in LDS (16-lane row groups)
    #pragma unroll
    for (int i = 0; i < 4; ++i) {
        float vv[4];
        float s = 0.f;
        #pragma unroll
        for (int j = 0; j < 4; ++j) { vv[j] = As[ty * 4 + i][tx * 4 + j]; s += vv[j]; }
        #pragma unroll
        for (int o = 1; o < 16; o <<= 1) s += __shfl_xor(s, o);
        float m = s * (1.0f / 64.0f);
        float qv = 0.f;
        #pragma unroll
        for (int j = 0; j < 4; ++j) { float d = vv[j] - m; qv += d * d; }
        #pragma unroll
        for (int o = 1; o < 16; o <<= 1) qv += __shfl_xor(qv, o);
        float rstd = rsqrtf(qv * (1.0f / 64.0f) + 1e-5f);
        #pragma unroll
        for (int j = 0; j < 4; ++j) {
            int col = tx * 4 + j;
            As[ty * 4 + i][col] = (vv[j] - m) * rstd * gin[col] + bin[col];
        }
    }
    __syncthreads();
    // gemm1: h = gelu(xm @ W1 + bb1)
    float acc[4][4] = {};
    #pragma unroll
    for (int k = 0; k < 64; ++k) {
        float a[4], w[4];
        #pragma unroll
        for (int i = 0; i < 4; ++i) a[i] = As[ty * 4 + i][k];
        #pragma unroll
        for (int j = 0; j < 4; ++j) w[j] = W1s[k][tx * 4 + j];
        #pragma unroll
        for (int i = 0; i < 4; ++i)
            #pragma unroll
            for (int j = 0; j < 4; ++j) acc[i][j] += a[i] * w[j];
    }
    __syncthreads();
    #pragma unroll
    for (int i = 0; i < 4; ++i)
        #pragma unroll
        for (int j = 0; j < 4; ++j)
            W1s[ty * 4 + i][tx * 4 + j] = gelu_exact(acc[i][j] + bb1[tx * 4 + j]);
    __syncthreads();
    // gemm2 + residual + output layernorm
    float acc2[4][4] = {};
    #pragma unroll
    for (int k = 0; k < 64; ++k) {
        float a[4], w[4];
        #pragma unroll
        for (int i = 0; i < 4; ++i) a[i] = W1s[ty * 4 + i][k];
        #pragma unroll
        for (int j = 0; j < 4; ++j) w[j] = W2s[k][tx * 4 + j];
        #pragma unroll
        for (int i = 0; i < 4; ++i)
            #pragma unroll
            for (int j = 0; j < 4; ++j) acc2[i][j] += a[i] * w[j];
    }
    #pragma unroll
    for (int i = 0; i < 4; ++i) {
        float v[4];
        float s = 0.f;
        #pragma unroll
        for (int j = 0; j < 4; ++j) {
            v[j] = acc2[i][j] + bb2[tx * 4 + j] + As[ty * 4 + i][tx * 4 + j];
            s += v[j];
        }
        #pragma unroll
        for (int o = 1; o < 16; o <<= 1) s += __shfl_xor(s, o);
        float m = s * (1.0f / 64.0f);
        float qv = 0.f;
        #pragma unroll
        for (int j = 0; j < 4; ++j) { float d = v[j] - m; qv += d * d; }
        #pragma unroll
        for (int o = 1; o < 16; o <<= 1) qv += __shfl_xor(qv, o);
        float rstd = rsqrtf(qv * (1.0f / 64.0f) + 1e-5f);
        long row = m0 + ty * 4 + i;
        #pragma unroll
        for (int j = 0; j < 4; ++j) {
            int col = tx * 4 + j;
            out[row * 64 + col] = (v[j] - m) * rstd * gout[col] + bln[col];
        }
    }
}

// ---------------------------------------------------------------- l1: avcat residual + input-LN + MLP + output-LN
__global__ __launch_bounds__(256) void k_mlp_av(
    const float* __restrict__ xn, const float* __restrict__ avcat,
    const float* __restrict__ boutv,
    const float* __restrict__ gin, const float* __restrict__ bin,
    const float* __restrict__ W1, const float* __restrict__ bb1,
    const float* __restrict__ W2, const float* __restrict__ bb2,
    const float* __restrict__ gout, const float* __restrict__ bln,
    float* __restrict__ out)
{
    __shared__ float As[64][65];
    __shared__ float W1s[64][65];
    __shared__ float W2s[64][65];
    int tid = threadIdx.x;
    int m0 = blockIdx.x * 64;
    #pragma unroll
    for (int it = 0; it < 16; ++it) {
        int idx = tid + it * 256;
        int r = idx >> 6, c = idx & 63;
        long row = m0 + r;
        int n = (int)(row & 4095), bb = (int)(row >> 12);
        As[r][c]  = xn[row * 64 + c] + avcat[(long)n * 128 + bb * 64 + c] + boutv[c];
        W1s[r][c] = W1[(long)r * 64 + c];
        W2s[r][c] = W2[(long)r * 64 + c];
    }
    __syncthreads();
    int tx = tid & 15, ty = tid >> 4;
    #pragma unroll
    for (int i = 0; i < 4; ++i) {
        float vv[4];
        float s = 0.f;
        #pragma unroll
        for (int j = 0; j < 4; ++j) { vv[j] = As[ty * 4 + i][tx * 4 + j]; s += vv[j]; }
        #pragma unroll
        for (int o = 1; o < 16; o <<= 1) s += __shfl_xor(s, o);
        float m = s * (1.0f / 64.0f);
        float qv = 0.f;
        #pragma unroll
        for (int j = 0; j < 4; ++j) { float d = vv[j] - m; qv += d * d; }
        #pragma unroll
        for (int o = 1; o < 16; o <<= 1) qv += __shfl_xor(qv, o);
        float rstd = rsqrtf(qv * (1.0f / 64.0f) + 1e-5f);
        #pragma unroll
        for (int j = 0; j < 4; ++j) {
            int col = tx * 4 + j;
            As[ty * 4 + i][col] = (vv[j] - m) * rstd * gin[col] + bin[col];
        }
    }
    __syncthreads();
    float acc[4][4] = {};
    #pragma unroll
    for (int k = 0; k < 64; ++k) {
        float a[4], w[4];
        #pragma unroll
        for (int i = 0; i < 4; ++i) a[i] = As[ty * 4 + i][k];
        #pragma unroll
        for (int j = 0; j < 4; ++j) w[j] = W1s[k][tx * 4 + j];
        #pragma unroll
        for (int i = 0; i < 4; ++i)
            #pragma unroll
            for (int j = 0; j < 4; ++j) acc[i][j] += a[i] * w[j];
    }
    __syncthreads();
    #pragma unroll
    for (int i = 0; i < 4; ++i)
        #pragma unroll
        for (int j = 0; j < 4; ++j)
            W1s[ty * 4 + i][tx * 4 + j] = gelu_exact(acc[i][j] + bb1[tx * 4 + j]);
    __syncthreads();
    float acc2[4][4] = {};
    #pragma unroll
    for (int k = 0; k < 64; ++k) {
        float a[4], w[4];
        #pragma unroll
        for (int i = 0; i < 4; ++i) a[i] = W1s[ty * 4 + i][k];
        #pragma unroll
        for (int j = 0; j < 4; ++j) w[j] = W2s[k][tx * 4 + j];
        #pragma unroll
        for (int i = 0; i < 4; ++i)
            #pragma unroll
            for (int j = 0; j < 4; ++j) acc2[i][j] += a[i] * w[j];
    }
    #pragma unroll
    for (int i = 0; i < 4; ++i) {
        float v[4];
        float s = 0.f;
        #pragma unroll
        for (int j = 0; j < 4; ++j) {
            v[j] = acc2[i][j] + bb2[tx * 4 + j] + As[ty * 4 + i][tx * 4 + j];
            s += v[j];
        }
        #pragma unroll
        for (int o = 1; o < 16; o <<= 1) s += __shfl_xor(s, o);
        float m = s * (1.0f / 64.0f);
        float qv = 0.f;
        #pragma unroll
        for (int j = 0; j < 4; ++j) { float d = v[j] - m; qv += d * d; }
        #pragma unroll
        for (int o = 1; o < 16; o <<= 1) qv += __shfl_xor(qv, o);
        float rstd = rsqrtf(qv * (1.0f / 64.0f) + 1e-5f);
        long row = m0 + ty * 4 + i;
        #pragma unroll
        for (int j = 0; j < 4; ++j) {
            int col = tx * 4 + j;
            out[row * 64 + col] = (v[j] - m) * rstd * gout[col] + bln[col];
        }
    }
}

// ---------------------------------------------------------------- launch
extern "C" void kernel_launch(void* const* d_in, const int* in_sizes, int n_in,
                              void* d_out, int out_size, void* d_ws, size_t ws_size,
                              hipStream_t stream)
{
    const float* embed = (const float*)d_in[0];
    const float* Aadj  = (const float*)d_in[1];
    const float* g1    = (const float*)d_in[2];
    const float* b1    = (const float*)d_in[3];
    const float* Wqkv  = (const float*)d_in[4];
    const float* Wout  = (const float*)d_in[5];
    const float* bout  = (const float*)d_in[6];
    const float* g2    = (const float*)d_in[7];
    const float* b2    = (const float*)d_in[8];
    const float* W1    = (const float*)d_in[9];
    const float* bb1   = (const float*)d_in[10];
    const float* W2    = (const float*)d_in[11];
    const float* bb2   = (const float*)d_in[12];
    const float* gf    = (const float*)d_in[13];
    const float* bff   = (const float*)d_in[14];

    // output regions (fp32): [x 524288 | attn 16777216 | ds 16777216]
    float* ox    = (float*)d_out;            // final x
    float* attnb = ox + 524288;              // attn output; l0 flash scratch; l1 strided bf16 dots
    float* dsb   = attnb + 16777216;         // ds output

    if (ws_size < (10ull << 20)) {           // diagnostic guard
        k_zero<<<133120, 256, 0, stream>>>(ox, 34078720l);
        return;
    }

    // workspace layout (non-aliased, 9.05 MB; mask +2 MB if available)
    char* ws = (char*)d_ws;
    float*          xn     = (float*)(ws + (0l << 20));            // 2 MB [8192,64]
    unsigned short* q      = (unsigned short*)(ws + (2l << 20));   // 2 MB [4096,256] bf16
    unsigned short* kmat   = (unsigned short*)(ws + (4l << 20));   // 2 MB [4096,256] bf16
    unsigned short* vwt    = (unsigned short*)(ws + (6l << 20));   // 1 MB [128,4096] bf16
    float*          OA     = (float*)(ws + (7l << 20));            // 2 MB [4096,128] l1 avcat accum
    float*          Wfold  = (float*)(ws + (9l << 20));            // 32 KB [2][64,64]
    unsigned long long* mask = (ws_size >= (12ull << 20))
        ? (unsigned long long*)(ws + (10l << 20)) : nullptr;       // 2 MB [4096,64]

    unsigned short* part   = (unsigned short*)attnb;               // 16 MB flash partials (l0)
    float*          fstats = attnb + 4194304;                      // 512 KB flash stats (l0)
    unsigned short* dots_b = (unsigned short*)attnb;               // l1: [4096] rows, stride 8192

    // -------- prologue: maskpack | Wfold(both) | LN(embed) | zero OA --------
    k_prologue<<<8224, 256, 0, stream>>>(Aadj, mask, Wqkv, Wout, Wfold,
                                         embed, g1, b1, xn, OA);

    // -------- layer 0 (attn/ds are scratch -> parts flash) --------
    k_qkx<<<dim3(64, 10), 256, 0, stream>>>(xn, Wqkv, Wfold, q, kmat, vwt);
    k_flash<<<dim3(32, NG), 256, 0, stream>>>(q, kmat, vwt, mask, Aadj, part, fstats);
    k_mlp_c<<<128, 256, 0, stream>>>(xn, part, fstats, bout, g2, b2,
                                     W1, bb1, W2, bb2,
                                     g1 + 64, b1 + 64, xn);                      // -> next xn

    // -------- layer 1 (attn/ds are required fp32 outputs) --------
    k_qkx<<<dim3(64, 10), 256, 0, stream>>>(xn, Wqkv + 64 * 768, Wfold + 4096, q, kmat, vwt);
    k_mfma_nt<<<dim3(32, 32), 256, 0, stream>>>(q, kmat, dots_b, 8192, 256, 0.125f);
    k_softmax_io<<<4096, 256, 0, stream>>>(dots_b, Aadj, mask, attnb, dsb);
    k_mfma_splitk<<<dim3(32, 8), 256, 0, stream>>>(attnb, vwt, OA);
    k_mlp_av<<<128, 256, 0, stream>>>(xn, OA, bout + 64, g2 + 64, b2 + 64,
                                      W1 + 4096, bb1 + 64, W2 + 4096, bb2 + 64,
                                      gf, bff, ox);                              // final LN -> out
}